// Round 2
// baseline (2541.864 us; speedup 1.0000x reference)
//
#include <hip/hip_runtime.h>
#include <math.h>

#define N_NODES 20000
#define N_EDGES 320000
#define TOT_E   340000      // E + N self loops
#define IN_F    512
#define HC      512         // H*C
#define NHEAD   4
#define CHAN    128
#define NEG_SLOPE 0.2f
#define BN_EPS  1e-5f

// ---- float <-> ordered-uint encoding for atomicMax on floats ----
__device__ __forceinline__ unsigned enc_f(float f) {
  unsigned u = __float_as_uint(f);
  return (u & 0x80000000u) ? ~u : (u | 0x80000000u);
}
__device__ __forceinline__ float dec_f(unsigned k) {
  unsigned u = (k & 0x80000000u) ? (k ^ 0x80000000u) : ~k;
  return __uint_as_float(u);
}

// ---- column means (sums) of edge_attr [E,4] ----
__global__ void edge_mean_kernel(const float* __restrict__ EA, float* __restrict__ msum) {
  float s0 = 0.f, s1 = 0.f, s2 = 0.f, s3 = 0.f;
  for (int i = blockIdx.x * blockDim.x + threadIdx.x; i < N_EDGES;
       i += gridDim.x * blockDim.x) {
    const float4 v = *(const float4*)&EA[(size_t)i * 4];
    s0 += v.x; s1 += v.y; s2 += v.z; s3 += v.w;
  }
#pragma unroll
  for (int m = 32; m >= 1; m >>= 1) {
    s0 += __shfl_down(s0, m); s1 += __shfl_down(s1, m);
    s2 += __shfl_down(s2, m); s3 += __shfl_down(s3, m);
  }
  __shared__ float red[4][4];
  const int lane = threadIdx.x & 63, wid = threadIdx.x >> 6;
  if (lane == 0) { red[wid][0] = s0; red[wid][1] = s1; red[wid][2] = s2; red[wid][3] = s3; }
  __syncthreads();
  if (threadIdx.x < 4) {
    float v = red[0][threadIdx.x] + red[1][threadIdx.x] + red[2][threadIdx.x] + red[3][threadIdx.x];
    atomicAdd(&msum[threadIdx.x], v);
  }
}

// ---- q[d][h] = sum_c W_edge[d, h*C+c] * att_edge[h, c]  (4x4) ----
__global__ void qmat_kernel(const float* __restrict__ We, const float* __restrict__ aedg,
                            float* __restrict__ q) {
  const int d = blockIdx.x >> 2, h = blockIdx.x & 3, lane = threadIdx.x; // 64 threads
  const int base = h * CHAN + lane * 2;
  float v = We[d * HC + base] * aedg[base] + We[d * HC + base + 1] * aedg[base + 1];
#pragma unroll
  for (int m = 32; m >= 1; m >>= 1) v += __shfl_down(v, m);
  if (lane == 0) q[d * 4 + h] = v;
}

// ---- h = x @ W : (20000,512)x(512,512) f32, 128x128 tile, 8x8 microtile ----
__global__ __launch_bounds__(256) void gemm_h_kernel(const float* __restrict__ X,
                                                     const float* __restrict__ W,
                                                     float* __restrict__ Hout) {
  __shared__ float As[16][128];   // k-major (transposed A tile)
  __shared__ float Bs[16][128];
  const int tid = threadIdx.x;
  const int bm = blockIdx.x * 128;
  const int bn = blockIdx.y * 128;
  const int tm = (tid >> 4) << 3;        // 0..120
  const int tn = (tid & 15) << 3;        // 0..120
  const int ar = tid >> 1;               // 0..127
  const int ac = (tid & 1) << 3;         // 0 or 8
  const int br = tid >> 4;               // 0..15
  const int bc = (tid & 15) << 3;        // 0..120
  const int arow = bm + ar;
  float acc[8][8] = {};
  for (int k0 = 0; k0 < IN_F; k0 += 16) {
    float4 a0 = {0, 0, 0, 0}, a1 = {0, 0, 0, 0};
    if (arow < N_NODES) {
      a0 = *(const float4*)&X[(size_t)arow * IN_F + k0 + ac];
      a1 = *(const float4*)&X[(size_t)arow * IN_F + k0 + ac + 4];
    }
    const float4 b0 = *(const float4*)&W[(size_t)(k0 + br) * HC + bn + bc];
    const float4 b1 = *(const float4*)&W[(size_t)(k0 + br) * HC + bn + bc + 4];
    __syncthreads();
    As[ac + 0][ar] = a0.x; As[ac + 1][ar] = a0.y; As[ac + 2][ar] = a0.z; As[ac + 3][ar] = a0.w;
    As[ac + 4][ar] = a1.x; As[ac + 5][ar] = a1.y; As[ac + 6][ar] = a1.z; As[ac + 7][ar] = a1.w;
    *(float4*)&Bs[br][bc] = b0;
    *(float4*)&Bs[br][bc + 4] = b1;
    __syncthreads();
#pragma unroll
    for (int k = 0; k < 16; ++k) {
      float a[8], b[8];
      *(float4*)&a[0] = *(const float4*)&As[k][tm];
      *(float4*)&a[4] = *(const float4*)&As[k][tm + 4];
      *(float4*)&b[0] = *(const float4*)&Bs[k][tn];
      *(float4*)&b[4] = *(const float4*)&Bs[k][tn + 4];
#pragma unroll
      for (int i = 0; i < 8; ++i)
#pragma unroll
        for (int j = 0; j < 8; ++j) acc[i][j] += a[i] * b[j];
    }
  }
#pragma unroll
  for (int i = 0; i < 8; ++i) {
    const int row = bm + tm + i;
    if (row < N_NODES) {
      float4 v0 = {acc[i][0], acc[i][1], acc[i][2], acc[i][3]};
      float4 v1 = {acc[i][4], acc[i][5], acc[i][6], acc[i][7]};
      *(float4*)&Hout[(size_t)row * HC + bn + tn] = v0;
      *(float4*)&Hout[(size_t)row * HC + bn + tn + 4] = v1;
    }
  }
}

// ---- per-node head dots: a_src/a_dst [N,4]; one wave per node ----
__global__ void node_att_kernel(const float* __restrict__ Hm,
                                const float* __restrict__ att_s,
                                const float* __restrict__ att_d,
                                float* __restrict__ a_src, float* __restrict__ a_dst) {
  const int n = blockIdx.x * 4 + (threadIdx.x >> 6);  // 4 waves/block, exact 20000
  const int lane = threadIdx.x & 63;
  const int j = lane * 8;                              // head = lane>>4 (128ch = 16 lanes)
  const float4 h0 = *(const float4*)&Hm[(size_t)n * HC + j];
  const float4 h1 = *(const float4*)&Hm[(size_t)n * HC + j + 4];
  const float4 s0 = *(const float4*)&att_s[j];
  const float4 s1 = *(const float4*)&att_s[j + 4];
  const float4 d0 = *(const float4*)&att_d[j];
  const float4 d1 = *(const float4*)&att_d[j + 4];
  float s = h0.x * s0.x + h0.y * s0.y + h0.z * s0.z + h0.w * s0.w +
            h1.x * s1.x + h1.y * s1.y + h1.z * s1.z + h1.w * s1.w;
  float d = h0.x * d0.x + h0.y * d0.y + h0.z * d0.z + h0.w * d0.w +
            h1.x * d1.x + h1.y * d1.y + h1.z * d1.z + h1.w * d1.w;
#pragma unroll
  for (int m = 8; m >= 1; m >>= 1) { s += __shfl_xor(s, m); d += __shfl_xor(d, m); }
  if ((lane & 15) == 0) {
    const int h = lane >> 4;
    a_src[n * 4 + h] = s;
    a_dst[n * 4 + h] = d;
  }
}

// ---- per-edge alpha (leaky-relu'd) + segment max via atomicMax ----
__global__ void alpha_kernel(const int* __restrict__ EI, const float* __restrict__ EA,
                             const float* __restrict__ a_src, const float* __restrict__ a_dst,
                             const float* __restrict__ msum, const float* __restrict__ q,
                             float* __restrict__ alpha, unsigned* __restrict__ amax) {
  const int k = blockIdx.x * blockDim.x + threadIdx.x;
  if (k >= TOT_E) return;
  int s, d;
  float e0, e1, e2, e3;
  if (k < N_EDGES) {
    s = EI[k]; d = EI[N_EDGES + k];
    const float4 e = *(const float4*)&EA[(size_t)k * 4];
    e0 = e.x; e1 = e.y; e2 = e.z; e3 = e.w;
  } else {
    s = d = k - N_EDGES;
    const float inv = 1.0f / (float)N_EDGES;
    e0 = msum[0] * inv; e1 = msum[1] * inv; e2 = msum[2] * inv; e3 = msum[3] * inv;
  }
  const float4 as = *(const float4*)&a_src[s * 4];
  const float4 ad = *(const float4*)&a_dst[d * 4];
  float al[4];
  const float asv[4] = {as.x, as.y, as.z, as.w};
  const float adv[4] = {ad.x, ad.y, ad.z, ad.w};
#pragma unroll
  for (int h = 0; h < 4; ++h) {
    float ae = e0 * q[h] + e1 * q[4 + h] + e2 * q[8 + h] + e3 * q[12 + h];
    float a = asv[h] + adv[h] + ae;
    a = (a >= 0.f) ? a : NEG_SLOPE * a;
    al[h] = a;
    atomicMax(&amax[d * 4 + h], enc_f(a));
  }
  float4 o = {al[0], al[1], al[2], al[3]};
  *(float4*)&alpha[(size_t)k * 4] = o;
}

// ---- ex = exp(alpha - amax[dst]); denom[dst] += ex ----
__global__ void exp_kernel(const int* __restrict__ EI, float* __restrict__ alpha,
                           const unsigned* __restrict__ amax, float* __restrict__ denom) {
  const int k = blockIdx.x * blockDim.x + threadIdx.x;
  if (k >= TOT_E) return;
  const int d = (k < N_EDGES) ? EI[N_EDGES + k] : (k - N_EDGES);
  float4 al = *(const float4*)&alpha[(size_t)k * 4];
  const float m0 = dec_f(amax[d * 4 + 0]);
  const float m1 = dec_f(amax[d * 4 + 1]);
  const float m2 = dec_f(amax[d * 4 + 2]);
  const float m3 = dec_f(amax[d * 4 + 3]);
  al.x = expf(al.x - m0); al.y = expf(al.y - m1);
  al.z = expf(al.z - m2); al.w = expf(al.w - m3);
  *(float4*)&alpha[(size_t)k * 4] = al;
  atomicAdd(&denom[d * 4 + 0], al.x);
  atomicAdd(&denom[d * 4 + 1], al.y);
  atomicAdd(&denom[d * 4 + 2], al.z);
  atomicAdd(&denom[d * 4 + 3], al.w);
}

// ---- initialize out with the self-loop message (covers every element) ----
__global__ __launch_bounds__(128) void selfloop_kernel(const float* __restrict__ Hm,
                                                       const float* __restrict__ alpha,
                                                       const float* __restrict__ denom,
                                                       float* __restrict__ out) {
  const int n = blockIdx.x;
  const int t = threadIdx.x;          // 128 threads -> 4 floats each
  const int head = t >> 5;
  const float w = alpha[(size_t)(N_EDGES + n) * 4 + head] / (denom[n * 4 + head] + 1e-16f);
  const float4 hv = *(const float4*)&Hm[(size_t)n * HC + t * 4];
  float4 o = {hv.x * w, hv.y * w, hv.z * w, hv.w * w};
  *(float4*)&out[(size_t)n * HC + t * 4] = o;
}

// ---- accumulate real-edge messages with float atomics ----
__global__ __launch_bounds__(128) void aggregate_kernel(const int* __restrict__ EI,
                                                        const float* __restrict__ Hm,
                                                        const float* __restrict__ alpha,
                                                        const float* __restrict__ denom,
                                                        float* __restrict__ out) {
  __shared__ float w4[4];
  __shared__ int ss[2];
  const int e = blockIdx.x;
  const int t = threadIdx.x;          // 128
  if (t < 4) {
    const int d = EI[N_EDGES + e];
    w4[t] = alpha[(size_t)e * 4 + t] / (denom[d * 4 + t] + 1e-16f);
    if (t == 0) { ss[0] = EI[e]; ss[1] = d; }
  }
  __syncthreads();
  const int s = ss[0], d = ss[1];
  const float w = w4[t >> 5];
  const float4 hv = *(const float4*)&Hm[(size_t)s * HC + t * 4];
  float* op = &out[(size_t)d * HC + t * 4];
  atomicAdd(op + 0, hv.x * w);
  atomicAdd(op + 1, hv.y * w);
  atomicAdd(op + 2, hv.z * w);
  atomicAdd(op + 3, hv.w * w);
}

// ---- BN column sums / sums of squares ----
__global__ void bn_stats_kernel(const float* __restrict__ out,
                                float* __restrict__ colsum, float* __restrict__ colsq) {
  const int t = threadIdx.x;          // 256 threads -> 2 channels each
  const int j = t * 2;
  float s0 = 0.f, s1 = 0.f, q0 = 0.f, q1 = 0.f;
  for (int r = blockIdx.x; r < N_NODES; r += gridDim.x) {
    const float2 v = *(const float2*)&out[(size_t)r * HC + j];
    s0 += v.x; s1 += v.y; q0 += v.x * v.x; q1 += v.y * v.y;
  }
  atomicAdd(&colsum[j], s0);
  atomicAdd(&colsum[j + 1], s1);
  atomicAdd(&colsq[j], q0);
  atomicAdd(&colsq[j + 1], q1);
}

// ---- fold BN into per-channel scale/shift (bias cancels exactly) ----
__global__ void bn_finalize_kernel(const float* __restrict__ colsum, const float* __restrict__ colsq,
                                   const float* __restrict__ gamma, const float* __restrict__ beta,
                                   float* __restrict__ scale, float* __restrict__ shift) {
  const int j = threadIdx.x;
  const float mu = colsum[j] * (1.0f / N_NODES);
  const float var = colsq[j] * (1.0f / N_NODES) - mu * mu;
  const float sc = gamma[j] * rsqrtf(var + BN_EPS);
  scale[j] = sc;
  shift[j] = beta[j] - mu * sc;
}

__global__ void bn_apply_kernel(float* __restrict__ out, const float* __restrict__ scale,
                                const float* __restrict__ shift) {
  const int i = blockIdx.x * blockDim.x + threadIdx.x;   // float4 index
  if (i >= N_NODES * HC / 4) return;
  const int j4 = (i & (HC / 4 - 1)) * 4;
  float4 v = ((const float4*)out)[i];
  const float4 sc = *(const float4*)&scale[j4];
  const float4 sh = *(const float4*)&shift[j4];
  v.x = v.x * sc.x + sh.x; v.y = v.y * sc.y + sh.y;
  v.z = v.z * sc.z + sh.z; v.w = v.w * sc.w + sh.w;
  ((float4*)out)[i] = v;
}

extern "C" void kernel_launch(void* const* d_in, const int* in_sizes, int n_in,
                              void* d_out, int out_size, void* d_ws, size_t ws_size,
                              hipStream_t stream) {
  const float* x     = (const float*)d_in[0];
  const int*   ei    = (const int*)d_in[1];
  const float* ea    = (const float*)d_in[2];
  const float* W     = (const float*)d_in[3];
  const float* We    = (const float*)d_in[4];
  const float* att_s = (const float*)d_in[5];
  const float* att_d = (const float*)d_in[6];
  const float* att_e = (const float*)d_in[7];
  // d_in[8] = bias: cancels exactly in BatchNorm -> unused
  const float* gamma = (const float*)d_in[9];
  const float* beta  = (const float*)d_in[10];
  float* out = (float*)d_out;
  float* ws  = (float*)d_ws;

  // workspace layout (floats)
  float*    h_buf  = ws;                                   // N*512
  float*    a_src  = h_buf + (size_t)N_NODES * HC;         // N*4
  float*    a_dst  = a_src + N_NODES * NHEAD;              // N*4
  float*    alpha  = a_dst + N_NODES * NHEAD;              // TOT_E*4
  float*    denom  = alpha + (size_t)TOT_E * NHEAD;        // N*4   (zeroed)
  unsigned* amax   = (unsigned*)(denom + N_NODES * NHEAD); // N*4   (zeroed; 0 == -inf key)
  float*    msum   = (float*)(amax + N_NODES * NHEAD);     // 4     (zeroed)
  float*    colsum = msum + 4;                             // 512   (zeroed)
  float*    colsq  = colsum + HC;                          // 512   (zeroed)
  float*    qm     = colsq + HC;                           // 16
  float*    scale  = qm + 16;                              // 512
  float*    shift  = scale + HC;                           // 512

  // re-zero all accumulators every call (inside the captured graph)
  const size_t zero_bytes = (size_t)(N_NODES * NHEAD * 2 + 4 + HC * 2) * sizeof(float);
  hipMemsetAsync(denom, 0, zero_bytes, stream);

  edge_mean_kernel<<<256, 256, 0, stream>>>(ea, msum);
  qmat_kernel<<<16, 64, 0, stream>>>(We, att_e, qm);
  gemm_h_kernel<<<dim3((N_NODES + 127) / 128, HC / 128), 256, 0, stream>>>(x, W, h_buf);
  node_att_kernel<<<N_NODES / 4, 256, 0, stream>>>(h_buf, att_s, att_d, a_src, a_dst);
  alpha_kernel<<<(TOT_E + 255) / 256, 256, 0, stream>>>(ei, ea, a_src, a_dst, msum, qm, alpha, amax);
  exp_kernel<<<(TOT_E + 255) / 256, 256, 0, stream>>>(ei, alpha, amax, denom);
  selfloop_kernel<<<N_NODES, 128, 0, stream>>>(h_buf, alpha, denom, out);
  aggregate_kernel<<<N_EDGES, 128, 0, stream>>>(ei, h_buf, alpha, denom, out);
  bn_stats_kernel<<<256, 256, 0, stream>>>(out, colsum, colsq);
  bn_finalize_kernel<<<1, HC, 0, stream>>>(colsum, colsq, gamma, beta, scale, shift);
  bn_apply_kernel<<<(N_NODES * HC / 4 + 255) / 256, 256, 0, stream>>>(out, scale, shift);
}

// Round 3
// 563.839 us; speedup vs baseline: 4.5081x; 4.5081x over previous
//
#include <hip/hip_runtime.h>
#include <math.h>

#define N_NODES 20000
#define N_EDGES 320000
#define TOT_E   340000      // E + N self loops
#define IN_F    512
#define HC      512         // H*C
#define NHEAD   4
#define CHAN    128
#define NEG_SLOPE 0.2f
#define BN_EPS  1e-5f

// ---- float <-> ordered-uint encoding for atomicMax on floats ----
__device__ __forceinline__ unsigned enc_f(float f) {
  unsigned u = __float_as_uint(f);
  return (u & 0x80000000u) ? ~u : (u | 0x80000000u);
}
__device__ __forceinline__ float dec_f(unsigned k) {
  unsigned u = (k & 0x80000000u) ? (k ^ 0x80000000u) : ~k;
  return __uint_as_float(u);
}

// ---- column means (sums) of edge_attr [E,4] ----
__global__ void edge_mean_kernel(const float* __restrict__ EA, float* __restrict__ msum) {
  float s0 = 0.f, s1 = 0.f, s2 = 0.f, s3 = 0.f;
  for (int i = blockIdx.x * blockDim.x + threadIdx.x; i < N_EDGES;
       i += gridDim.x * blockDim.x) {
    const float4 v = *(const float4*)&EA[(size_t)i * 4];
    s0 += v.x; s1 += v.y; s2 += v.z; s3 += v.w;
  }
#pragma unroll
  for (int m = 32; m >= 1; m >>= 1) {
    s0 += __shfl_down(s0, m); s1 += __shfl_down(s1, m);
    s2 += __shfl_down(s2, m); s3 += __shfl_down(s3, m);
  }
  __shared__ float red[4][4];
  const int lane = threadIdx.x & 63, wid = threadIdx.x >> 6;
  if (lane == 0) { red[wid][0] = s0; red[wid][1] = s1; red[wid][2] = s2; red[wid][3] = s3; }
  __syncthreads();
  if (threadIdx.x < 4) {
    float v = red[0][threadIdx.x] + red[1][threadIdx.x] + red[2][threadIdx.x] + red[3][threadIdx.x];
    atomicAdd(&msum[threadIdx.x], v);
  }
}

// ---- q[d][h] = sum_c W_edge[d, h*C+c] * att_edge[h, c]  (4x4) ----
__global__ void qmat_kernel(const float* __restrict__ We, const float* __restrict__ aedg,
                            float* __restrict__ q) {
  const int d = blockIdx.x >> 2, h = blockIdx.x & 3, lane = threadIdx.x; // 64 threads
  const int base = h * CHAN + lane * 2;
  float v = We[d * HC + base] * aedg[base] + We[d * HC + base + 1] * aedg[base + 1];
#pragma unroll
  for (int m = 32; m >= 1; m >>= 1) v += __shfl_down(v, m);
  if (lane == 0) q[d * 4 + h] = v;
}

// ---- in-degree histogram over real edges ----
__global__ void deg_kernel(const int* __restrict__ EI, int* __restrict__ deg) {
  const int e = blockIdx.x * blockDim.x + threadIdx.x;
  if (e >= N_EDGES) return;
  atomicAdd(&deg[EI[N_EDGES + e]], 1);
}

// ---- exclusive prefix sum over deg[20000] -> rowstart[20001]; one block/1024thr ----
__global__ __launch_bounds__(1024) void scan_kernel(const int* __restrict__ deg,
                                                    int* __restrict__ rowstart) {
  __shared__ int part[1024];
  const int t = threadIdx.x;
  const int base = t * 20;
  int local[20];
  int s = 0;
#pragma unroll
  for (int i = 0; i < 20; ++i) {
    const int idx = base + i;
    const int v = (idx < N_NODES) ? deg[idx] : 0;
    local[i] = s;           // exclusive within chunk
    s += v;
  }
  part[t] = s;
  __syncthreads();
  for (int off = 1; off < 1024; off <<= 1) {
    const int v = (t >= off) ? part[t - off] : 0;
    __syncthreads();
    part[t] += v;
    __syncthreads();
  }
  const int excl = (t > 0) ? part[t - 1] : 0;
#pragma unroll
  for (int i = 0; i < 20; ++i) {
    const int idx = base + i;
    if (idx < N_NODES) rowstart[idx] = excl + local[i];
  }
  if (t == 1023) rowstart[N_NODES] = part[1023];
}

// ---- scatter edges into CSR order by destination ----
__global__ void scatter_kernel(const int* __restrict__ EI, const int* __restrict__ rowstart,
                               int* __restrict__ cnt, int* __restrict__ csr_src,
                               int* __restrict__ csr_eid) {
  const int e = blockIdx.x * blockDim.x + threadIdx.x;
  if (e >= N_EDGES) return;
  const int d = EI[N_EDGES + e];
  const int pos = rowstart[d] + atomicAdd(&cnt[d], 1);
  csr_src[pos] = EI[e];
  csr_eid[pos] = e;
}

// ---- h = x @ W : (20000,512)x(512,512) f32, 128x128 tile, 8x8 microtile ----
__global__ __launch_bounds__(256) void gemm_h_kernel(const float* __restrict__ X,
                                                     const float* __restrict__ W,
                                                     float* __restrict__ Hout) {
  __shared__ float As[16][128];   // k-major (transposed A tile)
  __shared__ float Bs[16][128];
  const int tid = threadIdx.x;
  const int bm = blockIdx.x * 128;
  const int bn = blockIdx.y * 128;
  const int tm = (tid >> 4) << 3;        // 0..120
  const int tn = (tid & 15) << 3;        // 0..120
  const int ar = tid >> 1;               // 0..127
  const int ac = (tid & 1) << 3;         // 0 or 8
  const int br = tid >> 4;               // 0..15
  const int bc = (tid & 15) << 3;        // 0..120
  const int arow = bm + ar;
  float acc[8][8] = {};
  for (int k0 = 0; k0 < IN_F; k0 += 16) {
    float4 a0 = {0, 0, 0, 0}, a1 = {0, 0, 0, 0};
    if (arow < N_NODES) {
      a0 = *(const float4*)&X[(size_t)arow * IN_F + k0 + ac];
      a1 = *(const float4*)&X[(size_t)arow * IN_F + k0 + ac + 4];
    }
    const float4 b0 = *(const float4*)&W[(size_t)(k0 + br) * HC + bn + bc];
    const float4 b1 = *(const float4*)&W[(size_t)(k0 + br) * HC + bn + bc + 4];
    __syncthreads();
    As[ac + 0][ar] = a0.x; As[ac + 1][ar] = a0.y; As[ac + 2][ar] = a0.z; As[ac + 3][ar] = a0.w;
    As[ac + 4][ar] = a1.x; As[ac + 5][ar] = a1.y; As[ac + 6][ar] = a1.z; As[ac + 7][ar] = a1.w;
    *(float4*)&Bs[br][bc] = b0;
    *(float4*)&Bs[br][bc + 4] = b1;
    __syncthreads();
#pragma unroll
    for (int k = 0; k < 16; ++k) {
      float a[8], b[8];
      *(float4*)&a[0] = *(const float4*)&As[k][tm];
      *(float4*)&a[4] = *(const float4*)&As[k][tm + 4];
      *(float4*)&b[0] = *(const float4*)&Bs[k][tn];
      *(float4*)&b[4] = *(const float4*)&Bs[k][tn + 4];
#pragma unroll
      for (int i = 0; i < 8; ++i)
#pragma unroll
        for (int j = 0; j < 8; ++j) acc[i][j] += a[i] * b[j];
    }
  }
#pragma unroll
  for (int i = 0; i < 8; ++i) {
    const int row = bm + tm + i;
    if (row < N_NODES) {
      float4 v0 = {acc[i][0], acc[i][1], acc[i][2], acc[i][3]};
      float4 v1 = {acc[i][4], acc[i][5], acc[i][6], acc[i][7]};
      *(float4*)&Hout[(size_t)row * HC + bn + tn] = v0;
      *(float4*)&Hout[(size_t)row * HC + bn + tn + 4] = v1;
    }
  }
}

// ---- per-node head dots: a_src/a_dst [N,4]; one wave per node ----
__global__ void node_att_kernel(const float* __restrict__ Hm,
                                const float* __restrict__ att_s,
                                const float* __restrict__ att_d,
                                float* __restrict__ a_src, float* __restrict__ a_dst) {
  const int n = blockIdx.x * 4 + (threadIdx.x >> 6);  // 4 waves/block, exact 20000
  const int lane = threadIdx.x & 63;
  const int j = lane * 8;                              // head = lane>>4 (128ch = 16 lanes)
  const float4 h0 = *(const float4*)&Hm[(size_t)n * HC + j];
  const float4 h1 = *(const float4*)&Hm[(size_t)n * HC + j + 4];
  const float4 s0 = *(const float4*)&att_s[j];
  const float4 s1 = *(const float4*)&att_s[j + 4];
  const float4 d0 = *(const float4*)&att_d[j];
  const float4 d1 = *(const float4*)&att_d[j + 4];
  float s = h0.x * s0.x + h0.y * s0.y + h0.z * s0.z + h0.w * s0.w +
            h1.x * s1.x + h1.y * s1.y + h1.z * s1.z + h1.w * s1.w;
  float d = h0.x * d0.x + h0.y * d0.y + h0.z * d0.z + h0.w * d0.w +
            h1.x * d1.x + h1.y * d1.y + h1.z * d1.z + h1.w * d1.w;
#pragma unroll
  for (int m = 8; m >= 1; m >>= 1) { s += __shfl_xor(s, m); d += __shfl_xor(d, m); }
  if ((lane & 15) == 0) {
    const int h = lane >> 4;
    a_src[n * 4 + h] = s;
    a_dst[n * 4 + h] = d;
  }
}

// ---- per-edge alpha (leaky-relu'd) + segment max via atomicMax ----
__global__ void alpha_kernel(const int* __restrict__ EI, const float* __restrict__ EA,
                             const float* __restrict__ a_src, const float* __restrict__ a_dst,
                             const float* __restrict__ msum, const float* __restrict__ q,
                             float* __restrict__ alpha, unsigned* __restrict__ amax) {
  const int k = blockIdx.x * blockDim.x + threadIdx.x;
  if (k >= TOT_E) return;
  int s, d;
  float e0, e1, e2, e3;
  if (k < N_EDGES) {
    s = EI[k]; d = EI[N_EDGES + k];
    const float4 e = *(const float4*)&EA[(size_t)k * 4];
    e0 = e.x; e1 = e.y; e2 = e.z; e3 = e.w;
  } else {
    s = d = k - N_EDGES;
    const float inv = 1.0f / (float)N_EDGES;
    e0 = msum[0] * inv; e1 = msum[1] * inv; e2 = msum[2] * inv; e3 = msum[3] * inv;
  }
  const float4 as = *(const float4*)&a_src[s * 4];
  const float4 ad = *(const float4*)&a_dst[d * 4];
  float al[4];
  const float asv[4] = {as.x, as.y, as.z, as.w};
  const float adv[4] = {ad.x, ad.y, ad.z, ad.w};
#pragma unroll
  for (int h = 0; h < 4; ++h) {
    float ae = e0 * q[h] + e1 * q[4 + h] + e2 * q[8 + h] + e3 * q[12 + h];
    float a = asv[h] + adv[h] + ae;
    a = (a >= 0.f) ? a : NEG_SLOPE * a;
    al[h] = a;
    atomicMax(&amax[d * 4 + h], enc_f(a));
  }
  float4 o = {al[0], al[1], al[2], al[3]};
  *(float4*)&alpha[(size_t)k * 4] = o;
}

// ---- ex = exp(alpha - amax[dst]); denom[dst] += ex ----
__global__ void exp_kernel(const int* __restrict__ EI, float* __restrict__ alpha,
                           const unsigned* __restrict__ amax, float* __restrict__ denom) {
  const int k = blockIdx.x * blockDim.x + threadIdx.x;
  if (k >= TOT_E) return;
  const int d = (k < N_EDGES) ? EI[N_EDGES + k] : (k - N_EDGES);
  float4 al = *(const float4*)&alpha[(size_t)k * 4];
  const float m0 = dec_f(amax[d * 4 + 0]);
  const float m1 = dec_f(amax[d * 4 + 1]);
  const float m2 = dec_f(amax[d * 4 + 2]);
  const float m3 = dec_f(amax[d * 4 + 3]);
  al.x = expf(al.x - m0); al.y = expf(al.y - m1);
  al.z = expf(al.z - m2); al.w = expf(al.w - m3);
  *(float4*)&alpha[(size_t)k * 4] = al;
  atomicAdd(&denom[d * 4 + 0], al.x);
  atomicAdd(&denom[d * 4 + 1], al.y);
  atomicAdd(&denom[d * 4 + 2], al.z);
  atomicAdd(&denom[d * 4 + 3], al.w);
}

// ---- CSR gather-aggregate: one block per destination node, no atomics ----
// acc initialized with the self-loop message; out written exactly once.
__global__ __launch_bounds__(128) void csr_aggregate_kernel(
    const int* __restrict__ rowstart, const int* __restrict__ csr_src,
    const int* __restrict__ csr_eid, const float* __restrict__ Hm,
    const float* __restrict__ alpha, const float* __restrict__ denom,
    float* __restrict__ out) {
  const int n = blockIdx.x;
  const int t = threadIdx.x;            // 128 threads -> float4 each
  const int head = t >> 5;
  const int j = t * 4;
  const float dinv = 1.0f / (denom[n * 4 + head] + 1e-16f);
  const float wself = alpha[(size_t)(N_EDGES + n) * 4 + head] * dinv;
  const float4 hv = *(const float4*)&Hm[(size_t)n * HC + j];
  float4 acc = {hv.x * wself, hv.y * wself, hv.z * wself, hv.w * wself};
  const int beg = rowstart[n], end = rowstart[n + 1];
  int s_nxt = 0, e_nxt = 0;
  if (beg < end) { s_nxt = csr_src[beg]; e_nxt = csr_eid[beg]; }
  for (int idx = beg; idx < end; ++idx) {
    const int s = s_nxt, e = e_nxt;
    if (idx + 1 < end) { s_nxt = csr_src[idx + 1]; e_nxt = csr_eid[idx + 1]; }
    const float w = alpha[(size_t)e * 4 + head] * dinv;
    const float4 v = *(const float4*)&Hm[(size_t)s * HC + j];
    acc.x += v.x * w; acc.y += v.y * w; acc.z += v.z * w; acc.w += v.w * w;
  }
  *(float4*)&out[(size_t)n * HC + j] = acc;
}

// ---- BN column sums / sums of squares ----
__global__ void bn_stats_kernel(const float* __restrict__ out,
                                float* __restrict__ colsum, float* __restrict__ colsq) {
  const int t = threadIdx.x;          // 256 threads -> 2 channels each
  const int j = t * 2;
  float s0 = 0.f, s1 = 0.f, q0 = 0.f, q1 = 0.f;
  for (int r = blockIdx.x; r < N_NODES; r += gridDim.x) {
    const float2 v = *(const float2*)&out[(size_t)r * HC + j];
    s0 += v.x; s1 += v.y; q0 += v.x * v.x; q1 += v.y * v.y;
  }
  atomicAdd(&colsum[j], s0);
  atomicAdd(&colsum[j + 1], s1);
  atomicAdd(&colsq[j], q0);
  atomicAdd(&colsq[j + 1], q1);
}

// ---- fold BN into per-channel scale/shift (bias cancels exactly) ----
__global__ void bn_finalize_kernel(const float* __restrict__ colsum, const float* __restrict__ colsq,
                                   const float* __restrict__ gamma, const float* __restrict__ beta,
                                   float* __restrict__ scale, float* __restrict__ shift) {
  const int j = threadIdx.x;
  const float mu = colsum[j] * (1.0f / N_NODES);
  const float var = colsq[j] * (1.0f / N_NODES) - mu * mu;
  const float sc = gamma[j] * rsqrtf(var + BN_EPS);
  scale[j] = sc;
  shift[j] = beta[j] - mu * sc;
}

__global__ void bn_apply_kernel(float* __restrict__ out, const float* __restrict__ scale,
                                const float* __restrict__ shift) {
  const int i = blockIdx.x * blockDim.x + threadIdx.x;   // float4 index
  if (i >= N_NODES * HC / 4) return;
  const int j4 = (i & (HC / 4 - 1)) * 4;
  float4 v = ((const float4*)out)[i];
  const float4 sc = *(const float4*)&scale[j4];
  const float4 sh = *(const float4*)&shift[j4];
  v.x = v.x * sc.x + sh.x; v.y = v.y * sc.y + sh.y;
  v.z = v.z * sc.z + sh.z; v.w = v.w * sc.w + sh.w;
  ((float4*)out)[i] = v;
}

extern "C" void kernel_launch(void* const* d_in, const int* in_sizes, int n_in,
                              void* d_out, int out_size, void* d_ws, size_t ws_size,
                              hipStream_t stream) {
  const float* x     = (const float*)d_in[0];
  const int*   ei    = (const int*)d_in[1];
  const float* ea    = (const float*)d_in[2];
  const float* W     = (const float*)d_in[3];
  const float* We    = (const float*)d_in[4];
  const float* att_s = (const float*)d_in[5];
  const float* att_d = (const float*)d_in[6];
  const float* att_e = (const float*)d_in[7];
  // d_in[8] = bias: cancels exactly in BatchNorm -> unused
  const float* gamma = (const float*)d_in[9];
  const float* beta  = (const float*)d_in[10];
  float* out = (float*)d_out;
  float* ws  = (float*)d_ws;

  // workspace layout (floats/ints)
  float*    h_buf   = ws;                                    // N*512
  float*    a_src   = h_buf + (size_t)N_NODES * HC;          // N*4
  float*    a_dst   = a_src + N_NODES * NHEAD;               // N*4
  float*    alpha   = a_dst + N_NODES * NHEAD;               // TOT_E*4
  float*    qm      = alpha + (size_t)TOT_E * NHEAD;         // 16
  float*    scale   = qm + 16;                               // 512
  float*    shift   = scale + HC;                            // 512
  int*      rowstart= (int*)(shift + HC);                    // N+1 (+pad to 20004)
  int*      csr_src = rowstart + 20004;                      // E
  int*      csr_eid = csr_src + N_EDGES;                     // E
  // ---- zeroed-every-call block starts here ----
  float*    denom   = (float*)(csr_eid + N_EDGES);           // N*4
  unsigned* amax    = (unsigned*)(denom + N_NODES * NHEAD);  // N*4 (0 == -inf key)
  float*    msum    = (float*)(amax + N_NODES * NHEAD);      // 4
  float*    colsum  = msum + 4;                              // 512
  float*    colsq   = colsum + HC;                           // 512
  int*      deg     = (int*)(colsq + HC);                    // N
  int*      cnt     = deg + N_NODES;                         // N

  const size_t zero_bytes =
      (size_t)(N_NODES * NHEAD * 2 + 4 + HC * 2 + N_NODES * 2) * sizeof(float);
  hipMemsetAsync(denom, 0, zero_bytes, stream);

  edge_mean_kernel<<<256, 256, 0, stream>>>(ea, msum);
  qmat_kernel<<<16, 64, 0, stream>>>(We, att_e, qm);
  deg_kernel<<<(N_EDGES + 255) / 256, 256, 0, stream>>>(ei, deg);
  scan_kernel<<<1, 1024, 0, stream>>>(deg, rowstart);
  scatter_kernel<<<(N_EDGES + 255) / 256, 256, 0, stream>>>(ei, rowstart, cnt, csr_src, csr_eid);
  gemm_h_kernel<<<dim3((N_NODES + 127) / 128, HC / 128), 256, 0, stream>>>(x, W, h_buf);
  node_att_kernel<<<N_NODES / 4, 256, 0, stream>>>(h_buf, att_s, att_d, a_src, a_dst);
  alpha_kernel<<<(TOT_E + 255) / 256, 256, 0, stream>>>(ei, ea, a_src, a_dst, msum, qm, alpha, amax);
  exp_kernel<<<(TOT_E + 255) / 256, 256, 0, stream>>>(ei, alpha, amax, denom);
  csr_aggregate_kernel<<<N_NODES, 128, 0, stream>>>(rowstart, csr_src, csr_eid,
                                                    h_buf, alpha, denom, out);
  bn_stats_kernel<<<256, 256, 0, stream>>>(out, colsum, colsq);
  bn_finalize_kernel<<<1, HC, 0, stream>>>(colsum, colsq, gamma, beta, scale, shift);
  bn_apply_kernel<<<(N_NODES * HC / 4 + 255) / 256, 256, 0, stream>>>(out, scale, shift);
}

// Round 4
// 405.771 us; speedup vs baseline: 6.2643x; 1.3895x over previous
//
#include <hip/hip_runtime.h>
#include <math.h>

#define N_NODES 20000
#define N_EDGES 320000
#define TOT_E   340000      // E + N self loops
#define IN_F    512
#define HC      512         // H*C
#define NHEAD   4
#define CHAN    128
#define NEG_SLOPE 0.2f
#define BN_EPS  1e-5f

#define M16_PAD 1256        // 157 row-blocks * 8 = padded count of 16-row fragments

typedef short short8v __attribute__((ext_vector_type(8)));   // 8 bf16 (4 VGPRs)
typedef float f32x4  __attribute__((ext_vector_type(4)));

// ---- float <-> ordered-uint encoding for atomicMax on floats ----
__device__ __forceinline__ unsigned enc_f(float f) {
  unsigned u = __float_as_uint(f);
  return (u & 0x80000000u) ? ~u : (u | 0x80000000u);
}
__device__ __forceinline__ float dec_f(unsigned k) {
  unsigned u = (k & 0x80000000u) ? (k ^ 0x80000000u) : ~k;
  return __uint_as_float(u);
}

// ---- f32 -> bf16 bits, round-to-nearest-even ----
__device__ __forceinline__ unsigned short f2bf(float f) {
  unsigned u = __float_as_uint(f);
  return (unsigned short)((u + 0x7FFFu + ((u >> 16) & 1u)) >> 16);
}

// ---- column means (sums) of edge_attr [E,4] ----
__global__ void edge_mean_kernel(const float* __restrict__ EA, float* __restrict__ msum) {
  float s0 = 0.f, s1 = 0.f, s2 = 0.f, s3 = 0.f;
  for (int i = blockIdx.x * blockDim.x + threadIdx.x; i < N_EDGES;
       i += gridDim.x * blockDim.x) {
    const float4 v = *(const float4*)&EA[(size_t)i * 4];
    s0 += v.x; s1 += v.y; s2 += v.z; s3 += v.w;
  }
#pragma unroll
  for (int m = 32; m >= 1; m >>= 1) {
    s0 += __shfl_down(s0, m); s1 += __shfl_down(s1, m);
    s2 += __shfl_down(s2, m); s3 += __shfl_down(s3, m);
  }
  __shared__ float red[4][4];
  const int lane = threadIdx.x & 63, wid = threadIdx.x >> 6;
  if (lane == 0) { red[wid][0] = s0; red[wid][1] = s1; red[wid][2] = s2; red[wid][3] = s3; }
  __syncthreads();
  if (threadIdx.x < 4) {
    float v = red[0][threadIdx.x] + red[1][threadIdx.x] + red[2][threadIdx.x] + red[3][threadIdx.x];
    atomicAdd(&msum[threadIdx.x], v);
  }
}

// ---- q[d][h] = sum_c W_edge[d, h*C+c] * att_edge[h, c]  (4x4) ----
__global__ void qmat_kernel(const float* __restrict__ We, const float* __restrict__ aedg,
                            float* __restrict__ q) {
  const int d = blockIdx.x >> 2, h = blockIdx.x & 3, lane = threadIdx.x; // 64 threads
  const int base = h * CHAN + lane * 2;
  float v = We[d * HC + base] * aedg[base] + We[d * HC + base + 1] * aedg[base + 1];
#pragma unroll
  for (int m = 32; m >= 1; m >>= 1) v += __shfl_down(v, m);
  if (lane == 0) q[d * 4 + h] = v;
}

// ---- in-degree histogram over real edges ----
__global__ void deg_kernel(const int* __restrict__ EI, int* __restrict__ deg) {
  const int e = blockIdx.x * blockDim.x + threadIdx.x;
  if (e >= N_EDGES) return;
  atomicAdd(&deg[EI[N_EDGES + e]], 1);
}

// ---- exclusive prefix sum over deg[20000] -> rowstart[20001]; one block/1024thr ----
__global__ __launch_bounds__(1024) void scan_kernel(const int* __restrict__ deg,
                                                    int* __restrict__ rowstart) {
  __shared__ int part[1024];
  const int t = threadIdx.x;
  const int base = t * 20;
  int local[20];
  int s = 0;
#pragma unroll
  for (int i = 0; i < 20; ++i) {
    const int idx = base + i;
    const int v = (idx < N_NODES) ? deg[idx] : 0;
    local[i] = s;           // exclusive within chunk
    s += v;
  }
  part[t] = s;
  __syncthreads();
  for (int off = 1; off < 1024; off <<= 1) {
    const int v = (t >= off) ? part[t - off] : 0;
    __syncthreads();
    part[t] += v;
    __syncthreads();
  }
  const int excl = (t > 0) ? part[t - 1] : 0;
#pragma unroll
  for (int i = 0; i < 20; ++i) {
    const int idx = base + i;
    if (idx < N_NODES) rowstart[idx] = excl + local[i];
  }
  if (t == 1023) rowstart[N_NODES] = part[1023];
}

// ---- scatter edges into CSR order by destination ----
__global__ void scatter_kernel(const int* __restrict__ EI, const int* __restrict__ rowstart,
                               int* __restrict__ cnt, int* __restrict__ csr_src,
                               int* __restrict__ csr_eid) {
  const int e = blockIdx.x * blockDim.x + threadIdx.x;
  if (e >= N_EDGES) return;
  const int d = EI[N_EDGES + e];
  const int pos = rowstart[d] + atomicAdd(&cnt[d], 1);
  csr_src[pos] = EI[e];
  csr_eid[pos] = e;
}

// ---- pack x (f32, row-major) into per-lane MFMA A-fragment layout (bf16) ----
// Ap[((m16*16 + k32)*64 + l)*8 + j] = x[m16*16 + (l&15)][k32*32 + (l>>4)*8 + j]
// rows >= N_NODES zero-filled (M16_PAD covers 157 blocks of 128 rows).
__global__ void pack_a_kernel(const float* __restrict__ X, unsigned short* __restrict__ Ap) {
  const int tid = blockIdx.x * blockDim.x + threadIdx.x;   // exactly M16_PAD*16*64
  const int l = tid & 63;
  const int k32 = (tid >> 6) & 15;
  const int m16 = tid >> 10;
  const int row = m16 * 16 + (l & 15);
  const int k = k32 * 32 + ((l >> 4) << 3);
  unsigned short v[8] = {0, 0, 0, 0, 0, 0, 0, 0};
  if (row < N_NODES) {
    const float4 f0 = *(const float4*)&X[(size_t)row * IN_F + k];
    const float4 f1 = *(const float4*)&X[(size_t)row * IN_F + k + 4];
    v[0] = f2bf(f0.x); v[1] = f2bf(f0.y); v[2] = f2bf(f0.z); v[3] = f2bf(f0.w);
    v[4] = f2bf(f1.x); v[5] = f2bf(f1.y); v[6] = f2bf(f1.z); v[7] = f2bf(f1.w);
  }
  *(short8v*)&Ap[(size_t)tid * 8] = *(short8v*)v;
}

// ---- pack W (f32 [K,N] row-major) into per-lane MFMA B-fragment layout (bf16) ----
// Bp[((n16*16 + k32)*64 + l)*8 + j] = W[k32*32 + (l>>4)*8 + j][n16*16 + (l&15)]
__global__ void pack_b_kernel(const float* __restrict__ W, unsigned short* __restrict__ Bp) {
  const int tid = blockIdx.x * blockDim.x + threadIdx.x;   // 32*16*64 = 32768
  const int l = tid & 63;
  const int k32 = (tid >> 6) & 15;
  const int n16 = tid >> 10;
  const int col = n16 * 16 + (l & 15);
  const int k = k32 * 32 + ((l >> 4) << 3);
  unsigned short v[8];
#pragma unroll
  for (int j = 0; j < 8; ++j) v[j] = f2bf(W[(size_t)(k + j) * HC + col]);
  *(short8v*)&Bp[(size_t)tid * 8] = *(short8v*)v;
}

// ---- h = x @ W via bf16 MFMA; fragments straight from global, no LDS ----
__global__ __launch_bounds__(256) void mfma_gemm_kernel(const unsigned short* __restrict__ Ap_,
                                                        const unsigned short* __restrict__ Bp_,
                                                        float* __restrict__ Hout) {
  const short8v* __restrict__ Ap = (const short8v*)Ap_;
  const short8v* __restrict__ Bp = (const short8v*)Bp_;
  const int tid = threadIdx.x;
  const int l = tid & 63;
  const int w = tid >> 6;                 // 4 waves, 2x2
  const int wr = w >> 1, wc = w & 1;
  const int bm16 = blockIdx.x * 8 + wr * 4;   // 16-row fragment base (global)
  const int bn16 = blockIdx.y * 8 + wc * 4;   // 16-col fragment base
  f32x4 acc[4][4] = {};
#pragma unroll 2
  for (int kk = 0; kk < IN_F / 32; ++kk) {
    short8v a[4], b[4];
#pragma unroll
    for (int m = 0; m < 4; ++m) a[m] = Ap[((size_t)(bm16 + m) * 16 + kk) * 64 + l];
#pragma unroll
    for (int n = 0; n < 4; ++n) b[n] = Bp[((size_t)(bn16 + n) * 16 + kk) * 64 + l];
#pragma unroll
    for (int m = 0; m < 4; ++m)
#pragma unroll
      for (int n = 0; n < 4; ++n)
        acc[m][n] = __builtin_amdgcn_mfma_f32_16x16x32_bf16(a[m], b[n], acc[m][n], 0, 0, 0);
  }
  const int rbase = (l >> 4) * 4;   // C/D: col = l&15, row = (l>>4)*4 + r
  const int cl = l & 15;
#pragma unroll
  for (int m = 0; m < 4; ++m) {
#pragma unroll
    for (int r = 0; r < 4; ++r) {
      const int row = (bm16 + m) * 16 + rbase + r;
      if (row < N_NODES) {
#pragma unroll
        for (int n = 0; n < 4; ++n)
          Hout[(size_t)row * HC + (bn16 + n) * 16 + cl] = acc[m][n][r];
      }
    }
  }
}

// ---- per-node head dots: a_src/a_dst [N,4]; one wave per node ----
__global__ void node_att_kernel(const float* __restrict__ Hm,
                                const float* __restrict__ att_s,
                                const float* __restrict__ att_d,
                                float* __restrict__ a_src, float* __restrict__ a_dst) {
  const int n = blockIdx.x * 4 + (threadIdx.x >> 6);  // 4 waves/block, exact 20000
  const int lane = threadIdx.x & 63;
  const int j = lane * 8;                              // head = lane>>4 (128ch = 16 lanes)
  const float4 h0 = *(const float4*)&Hm[(size_t)n * HC + j];
  const float4 h1 = *(const float4*)&Hm[(size_t)n * HC + j + 4];
  const float4 s0 = *(const float4*)&att_s[j];
  const float4 s1 = *(const float4*)&att_s[j + 4];
  const float4 d0 = *(const float4*)&att_d[j];
  const float4 d1 = *(const float4*)&att_d[j + 4];
  float s = h0.x * s0.x + h0.y * s0.y + h0.z * s0.z + h0.w * s0.w +
            h1.x * s1.x + h1.y * s1.y + h1.z * s1.z + h1.w * s1.w;
  float d = h0.x * d0.x + h0.y * d0.y + h0.z * d0.z + h0.w * d0.w +
            h1.x * d1.x + h1.y * d1.y + h1.z * d1.z + h1.w * d1.w;
#pragma unroll
  for (int m = 8; m >= 1; m >>= 1) { s += __shfl_xor(s, m); d += __shfl_xor(d, m); }
  if ((lane & 15) == 0) {
    const int h = lane >> 4;
    a_src[n * 4 + h] = s;
    a_dst[n * 4 + h] = d;
  }
}

// ---- per-edge alpha (leaky-relu'd) + segment max via atomicMax ----
__global__ void alpha_kernel(const int* __restrict__ EI, const float* __restrict__ EA,
                             const float* __restrict__ a_src, const float* __restrict__ a_dst,
                             const float* __restrict__ msum, const float* __restrict__ q,
                             float* __restrict__ alpha, unsigned* __restrict__ amax) {
  const int k = blockIdx.x * blockDim.x + threadIdx.x;
  if (k >= TOT_E) return;
  int s, d;
  float e0, e1, e2, e3;
  if (k < N_EDGES) {
    s = EI[k]; d = EI[N_EDGES + k];
    const float4 e = *(const float4*)&EA[(size_t)k * 4];
    e0 = e.x; e1 = e.y; e2 = e.z; e3 = e.w;
  } else {
    s = d = k - N_EDGES;
    const float inv = 1.0f / (float)N_EDGES;
    e0 = msum[0] * inv; e1 = msum[1] * inv; e2 = msum[2] * inv; e3 = msum[3] * inv;
  }
  const float4 as = *(const float4*)&a_src[s * 4];
  const float4 ad = *(const float4*)&a_dst[d * 4];
  float al[4];
  const float asv[4] = {as.x, as.y, as.z, as.w};
  const float adv[4] = {ad.x, ad.y, ad.z, ad.w};
#pragma unroll
  for (int h = 0; h < 4; ++h) {
    float ae = e0 * q[h] + e1 * q[4 + h] + e2 * q[8 + h] + e3 * q[12 + h];
    float a = asv[h] + adv[h] + ae;
    a = (a >= 0.f) ? a : NEG_SLOPE * a;
    al[h] = a;
    atomicMax(&amax[d * 4 + h], enc_f(a));
  }
  float4 o = {al[0], al[1], al[2], al[3]};
  *(float4*)&alpha[(size_t)k * 4] = o;
}

// ---- ex = exp(alpha - amax[dst]); denom[dst] += ex ----
__global__ void exp_kernel(const int* __restrict__ EI, float* __restrict__ alpha,
                           const unsigned* __restrict__ amax, float* __restrict__ denom) {
  const int k = blockIdx.x * blockDim.x + threadIdx.x;
  if (k >= TOT_E) return;
  const int d = (k < N_EDGES) ? EI[N_EDGES + k] : (k - N_EDGES);
  float4 al = *(const float4*)&alpha[(size_t)k * 4];
  const float m0 = dec_f(amax[d * 4 + 0]);
  const float m1 = dec_f(amax[d * 4 + 1]);
  const float m2 = dec_f(amax[d * 4 + 2]);
  const float m3 = dec_f(amax[d * 4 + 3]);
  al.x = expf(al.x - m0); al.y = expf(al.y - m1);
  al.z = expf(al.z - m2); al.w = expf(al.w - m3);
  *(float4*)&alpha[(size_t)k * 4] = al;
  atomicAdd(&denom[d * 4 + 0], al.x);
  atomicAdd(&denom[d * 4 + 1], al.y);
  atomicAdd(&denom[d * 4 + 2], al.z);
  atomicAdd(&denom[d * 4 + 3], al.w);
}

// ---- CSR gather-aggregate: one block per destination node, no atomics ----
__global__ __launch_bounds__(128) void csr_aggregate_kernel(
    const int* __restrict__ rowstart, const int* __restrict__ csr_src,
    const int* __restrict__ csr_eid, const float* __restrict__ Hm,
    const float* __restrict__ alpha, const float* __restrict__ denom,
    float* __restrict__ out) {
  const int n = blockIdx.x;
  const int t = threadIdx.x;            // 128 threads -> float4 each
  const int head = t >> 5;
  const int j = t * 4;
  const float dinv = 1.0f / (denom[n * 4 + head] + 1e-16f);
  const float wself = alpha[(size_t)(N_EDGES + n) * 4 + head] * dinv;
  const float4 hv = *(const float4*)&Hm[(size_t)n * HC + j];
  float4 acc = {hv.x * wself, hv.y * wself, hv.z * wself, hv.w * wself};
  const int beg = rowstart[n], end = rowstart[n + 1];
  int s_nxt = 0, e_nxt = 0;
  if (beg < end) { s_nxt = csr_src[beg]; e_nxt = csr_eid[beg]; }
  for (int idx = beg; idx < end; ++idx) {
    const int s = s_nxt, e = e_nxt;
    if (idx + 1 < end) { s_nxt = csr_src[idx + 1]; e_nxt = csr_eid[idx + 1]; }
    const float w = alpha[(size_t)e * 4 + head] * dinv;
    const float4 v = *(const float4*)&Hm[(size_t)s * HC + j];
    acc.x += v.x * w; acc.y += v.y * w; acc.z += v.z * w; acc.w += v.w * w;
  }
  *(float4*)&out[(size_t)n * HC + j] = acc;
}

// ---- BN column sums / sums of squares ----
__global__ void bn_stats_kernel(const float* __restrict__ out,
                                float* __restrict__ colsum, float* __restrict__ colsq) {
  const int t = threadIdx.x;          // 256 threads -> 2 channels each
  const int j = t * 2;
  float s0 = 0.f, s1 = 0.f, q0 = 0.f, q1 = 0.f;
  for (int r = blockIdx.x; r < N_NODES; r += gridDim.x) {
    const float2 v = *(const float2*)&out[(size_t)r * HC + j];
    s0 += v.x; s1 += v.y; q0 += v.x * v.x; q1 += v.y * v.y;
  }
  atomicAdd(&colsum[j], s0);
  atomicAdd(&colsum[j + 1], s1);
  atomicAdd(&colsq[j], q0);
  atomicAdd(&colsq[j + 1], q1);
}

// ---- fold BN into per-channel scale/shift (bias cancels exactly) ----
__global__ void bn_finalize_kernel(const float* __restrict__ colsum, const float* __restrict__ colsq,
                                   const float* __restrict__ gamma, const float* __restrict__ beta,
                                   float* __restrict__ scale, float* __restrict__ shift) {
  const int j = threadIdx.x;
  const float mu = colsum[j] * (1.0f / N_NODES);
  const float var = colsq[j] * (1.0f / N_NODES) - mu * mu;
  const float sc = gamma[j] * rsqrtf(var + BN_EPS);
  scale[j] = sc;
  shift[j] = beta[j] - mu * sc;
}

__global__ void bn_apply_kernel(float* __restrict__ out, const float* __restrict__ scale,
                                const float* __restrict__ shift) {
  const int i = blockIdx.x * blockDim.x + threadIdx.x;   // float4 index
  if (i >= N_NODES * HC / 4) return;
  const int j4 = (i & (HC / 4 - 1)) * 4;
  float4 v = ((const float4*)out)[i];
  const float4 sc = *(const float4*)&scale[j4];
  const float4 sh = *(const float4*)&shift[j4];
  v.x = v.x * sc.x + sh.x; v.y = v.y * sc.y + sh.y;
  v.z = v.z * sc.z + sh.z; v.w = v.w * sc.w + sh.w;
  ((float4*)out)[i] = v;
}

extern "C" void kernel_launch(void* const* d_in, const int* in_sizes, int n_in,
                              void* d_out, int out_size, void* d_ws, size_t ws_size,
                              hipStream_t stream) {
  const float* x     = (const float*)d_in[0];
  const int*   ei    = (const int*)d_in[1];
  const float* ea    = (const float*)d_in[2];
  const float* W     = (const float*)d_in[3];
  const float* We    = (const float*)d_in[4];
  const float* att_s = (const float*)d_in[5];
  const float* att_d = (const float*)d_in[6];
  const float* att_e = (const float*)d_in[7];
  // d_in[8] = bias: cancels exactly in BatchNorm -> unused
  const float* gamma = (const float*)d_in[9];
  const float* beta  = (const float*)d_in[10];
  float* out = (float*)d_out;
  float* ws  = (float*)d_ws;

  // workspace layout (floats/ints/ushorts)
  float*    h_buf   = ws;                                    // N*512
  float*    a_src   = h_buf + (size_t)N_NODES * HC;          // N*4
  float*    a_dst   = a_src + N_NODES * NHEAD;               // N*4
  float*    alpha   = a_dst + N_NODES * NHEAD;               // TOT_E*4
  float*    qm      = alpha + (size_t)TOT_E * NHEAD;         // 16
  float*    scale   = qm + 16;                               // 512
  float*    shift   = scale + HC;                            // 512
  int*      rowstart= (int*)(shift + HC);                    // N+1 (+pad to 20004)
  int*      csr_src = rowstart + 20004;                      // E
  int*      csr_eid = csr_src + N_EDGES;                     // E
  // ---- zeroed-every-call block starts here ----
  float*    denom   = (float*)(csr_eid + N_EDGES);           // N*4
  unsigned* amax    = (unsigned*)(denom + N_NODES * NHEAD);  // N*4 (0 == -inf key)
  float*    msum    = (float*)(amax + N_NODES * NHEAD);      // 4
  float*    colsum  = msum + 4;                              // 512
  float*    colsq   = colsum + HC;                           // 512
  int*      deg     = (int*)(colsq + HC);                    // N
  int*      cnt     = deg + N_NODES;                         // N
  // ---- bf16 fragment buffers ----
  unsigned short* Ap = (unsigned short*)(cnt + N_NODES);     // M16_PAD*16*64*8 ush
  unsigned short* Bp = Ap + (size_t)M16_PAD * 16 * 64 * 8;   // 32*16*64*8 ush

  const size_t zero_bytes =
      (size_t)(N_NODES * NHEAD * 2 + 4 + HC * 2 + N_NODES * 2) * sizeof(float);
  hipMemsetAsync(denom, 0, zero_bytes, stream);

  edge_mean_kernel<<<256, 256, 0, stream>>>(ea, msum);
  qmat_kernel<<<16, 64, 0, stream>>>(We, att_e, qm);
  deg_kernel<<<(N_EDGES + 255) / 256, 256, 0, stream>>>(ei, deg);
  scan_kernel<<<1, 1024, 0, stream>>>(deg, rowstart);
  scatter_kernel<<<(N_EDGES + 255) / 256, 256, 0, stream>>>(ei, rowstart, cnt, csr_src, csr_eid);
  pack_a_kernel<<<M16_PAD * 16 * 64 / 256, 256, 0, stream>>>(x, Ap);
  pack_b_kernel<<<32 * 16 * 64 / 256, 256, 0, stream>>>(W, Bp);
  mfma_gemm_kernel<<<dim3(157, 4), 256, 0, stream>>>(Ap, Bp, h_buf);
  node_att_kernel<<<N_NODES / 4, 256, 0, stream>>>(h_buf, att_s, att_d, a_src, a_dst);
  alpha_kernel<<<(TOT_E + 255) / 256, 256, 0, stream>>>(ei, ea, a_src, a_dst, msum, qm, alpha, amax);
  exp_kernel<<<(TOT_E + 255) / 256, 256, 0, stream>>>(ei, alpha, amax, denom);
  csr_aggregate_kernel<<<N_NODES, 128, 0, stream>>>(rowstart, csr_src, csr_eid,
                                                    h_buf, alpha, denom, out);
  bn_stats_kernel<<<256, 256, 0, stream>>>(out, colsum, colsq);
  bn_finalize_kernel<<<1, HC, 0, stream>>>(colsum, colsq, gamma, beta, scale, shift);
  bn_apply_kernel<<<(N_NODES * HC / 4 + 255) / 256, 256, 0, stream>>>(out, scale, shift);
}

// Round 5
// 235.300 us; speedup vs baseline: 10.8026x; 1.7245x over previous
//
#include <hip/hip_runtime.h>
#include <math.h>

#define N_NODES 20000
#define N_EDGES 320000
#define TOT_E   340000      // E + N self loops
#define IN_F    512
#define HC      512         // H*C
#define NHEAD   4
#define CHAN    128
#define NEG_SLOPE 0.2f
#define BN_EPS  1e-5f

#define M16_PAD 1256        // 157 row-blocks * 8 = padded count of 16-row fragments

typedef short short8v __attribute__((ext_vector_type(8)));   // 8 bf16 (4 VGPRs)
typedef float f32x4  __attribute__((ext_vector_type(4)));
typedef unsigned short u16x4 __attribute__((ext_vector_type(4)));

// ---- f32 -> bf16 bits, round-to-nearest-even ----
__device__ __forceinline__ unsigned short f2bf(float f) {
  unsigned u = __float_as_uint(f);
  return (unsigned short)((u + 0x7FFFu + ((u >> 16) & 1u)) >> 16);
}
__device__ __forceinline__ float bf2f(unsigned short b) {
  return __uint_as_float(((unsigned)b) << 16);
}

// ---- fused: edge_attr column sums + in-degree histogram + qmat (blocks 0..15) ----
__global__ void prep_kernel(const float* __restrict__ EA, const int* __restrict__ EI,
                            const float* __restrict__ We, const float* __restrict__ aedg,
                            float* __restrict__ msum, int* __restrict__ deg,
                            float* __restrict__ qm) {
  // qmat: q[d][h] = sum_c W_edge[d, h*C+c] * att_edge[h, c]
  if (blockIdx.x < 16 && threadIdx.x < 64) {
    const int d = blockIdx.x >> 2, h = blockIdx.x & 3, lane = threadIdx.x;
    const int base = h * CHAN + lane * 2;
    float v = We[d * HC + base] * aedg[base] + We[d * HC + base + 1] * aedg[base + 1];
#pragma unroll
    for (int m = 32; m >= 1; m >>= 1) v += __shfl_down(v, m);
    if (lane == 0) qm[d * 4 + h] = v;
  }
  float s0 = 0.f, s1 = 0.f, s2 = 0.f, s3 = 0.f;
  for (int i = blockIdx.x * blockDim.x + threadIdx.x; i < N_EDGES;
       i += gridDim.x * blockDim.x) {
    const float4 v = *(const float4*)&EA[(size_t)i * 4];
    s0 += v.x; s1 += v.y; s2 += v.z; s3 += v.w;
    atomicAdd(&deg[EI[N_EDGES + i]], 1);
  }
#pragma unroll
  for (int m = 32; m >= 1; m >>= 1) {
    s0 += __shfl_down(s0, m); s1 += __shfl_down(s1, m);
    s2 += __shfl_down(s2, m); s3 += __shfl_down(s3, m);
  }
  __shared__ float red[4][4];
  const int lane = threadIdx.x & 63, wid = threadIdx.x >> 6;
  if (lane == 0) { red[wid][0] = s0; red[wid][1] = s1; red[wid][2] = s2; red[wid][3] = s3; }
  __syncthreads();
  if (threadIdx.x < 4) {
    float v = red[0][threadIdx.x] + red[1][threadIdx.x] + red[2][threadIdx.x] + red[3][threadIdx.x];
    atomicAdd(&msum[threadIdx.x], v);
  }
}

// ---- exclusive prefix sum over deg[20000] -> rowstart[20001]; one block/1024thr ----
__global__ __launch_bounds__(1024) void scan_kernel(const int* __restrict__ deg,
                                                    int* __restrict__ rowstart) {
  __shared__ int part[1024];
  const int t = threadIdx.x;
  const int base = t * 20;
  int local[20];
  int s = 0;
#pragma unroll
  for (int i = 0; i < 20; ++i) {
    const int idx = base + i;
    const int v = (idx < N_NODES) ? deg[idx] : 0;
    local[i] = s;           // exclusive within chunk
    s += v;
  }
  part[t] = s;
  __syncthreads();
  for (int off = 1; off < 1024; off <<= 1) {
    const int v = (t >= off) ? part[t - off] : 0;
    __syncthreads();
    part[t] += v;
    __syncthreads();
  }
  const int excl = (t > 0) ? part[t - 1] : 0;
#pragma unroll
  for (int i = 0; i < 20; ++i) {
    const int idx = base + i;
    if (idx < N_NODES) rowstart[idx] = excl + local[i];
  }
  if (t == 1023) rowstart[N_NODES] = part[1023];
}

// ---- pack A (x) and B (W) into per-lane MFMA bf16 fragment layouts ----
// B blocks: [0,128); A blocks: [128, 128+5024)
__global__ void pack_ab_kernel(const float* __restrict__ X, const float* __restrict__ W,
                               unsigned short* __restrict__ Ap, unsigned short* __restrict__ Bp) {
  if (blockIdx.x < 128) {
    const int tid = blockIdx.x * blockDim.x + threadIdx.x;   // 32768
    const int l = tid & 63;
    const int k32 = (tid >> 6) & 15;
    const int n16 = tid >> 10;
    const int col = n16 * 16 + (l & 15);
    const int k = k32 * 32 + ((l >> 4) << 3);
    unsigned short v[8];
#pragma unroll
    for (int j = 0; j < 8; ++j) v[j] = f2bf(W[(size_t)(k + j) * HC + col]);
    *(short8v*)&Bp[(size_t)tid * 8] = *(short8v*)v;
  } else {
    const int tid = (blockIdx.x - 128) * blockDim.x + threadIdx.x; // M16_PAD*16*64
    const int l = tid & 63;
    const int k32 = (tid >> 6) & 15;
    const int m16 = tid >> 10;
    const int row = m16 * 16 + (l & 15);
    const int k = k32 * 32 + ((l >> 4) << 3);
    unsigned short v[8] = {0, 0, 0, 0, 0, 0, 0, 0};
    if (row < N_NODES) {
      const float4 f0 = *(const float4*)&X[(size_t)row * IN_F + k];
      const float4 f1 = *(const float4*)&X[(size_t)row * IN_F + k + 4];
      v[0] = f2bf(f0.x); v[1] = f2bf(f0.y); v[2] = f2bf(f0.z); v[3] = f2bf(f0.w);
      v[4] = f2bf(f1.x); v[5] = f2bf(f1.y); v[6] = f2bf(f1.z); v[7] = f2bf(f1.w);
    }
    *(short8v*)&Ap[(size_t)tid * 8] = *(short8v*)v;
  }
}

// ---- h = x @ W via bf16 MFMA; writes h as bf16; fuses per-head att dots ----
// blockIdx.y == head (128 cols). a_src/a_dst computed exactly (f32 acc).
__global__ __launch_bounds__(256) void mfma_gemm_fused(const unsigned short* __restrict__ Ap_,
                                                       const unsigned short* __restrict__ Bp_,
                                                       const float* __restrict__ att_s,
                                                       const float* __restrict__ att_d,
                                                       unsigned short* __restrict__ H16,
                                                       float* __restrict__ a_src,
                                                       float* __restrict__ a_dst) {
  const short8v* __restrict__ Ap = (const short8v*)Ap_;
  const short8v* __restrict__ Bp = (const short8v*)Bp_;
  const int tid = threadIdx.x;
  const int l = tid & 63;
  const int w = tid >> 6;                 // 4 waves, 2x2
  const int wr = w >> 1, wc = w & 1;
  const int bm16 = blockIdx.x * 8 + wr * 4;   // 16-row fragment base (global)
  const int bn16 = blockIdx.y * 8 + wc * 4;   // 16-col fragment base
  const int head = blockIdx.y;
  f32x4 acc[4][4] = {};
#pragma unroll 2
  for (int kk = 0; kk < IN_F / 32; ++kk) {
    short8v a[4], b[4];
#pragma unroll
    for (int m = 0; m < 4; ++m) a[m] = Ap[((size_t)(bm16 + m) * 16 + kk) * 64 + l];
#pragma unroll
    for (int n = 0; n < 4; ++n) b[n] = Bp[((size_t)(bn16 + n) * 16 + kk) * 64 + l];
#pragma unroll
    for (int m = 0; m < 4; ++m)
#pragma unroll
      for (int n = 0; n < 4; ++n)
        acc[m][n] = __builtin_amdgcn_mfma_f32_16x16x32_bf16(a[m], b[n], acc[m][n], 0, 0, 0);
  }
  const int rbase = (l >> 4) * 4;   // C/D: col = l&15, row = (l>>4)*4 + r
  const int cl = l & 15;
  // ---- store h in bf16 ----
#pragma unroll
  for (int m = 0; m < 4; ++m) {
#pragma unroll
    for (int r = 0; r < 4; ++r) {
      const int row = (bm16 + m) * 16 + rbase + r;
      if (row < N_NODES) {
#pragma unroll
        for (int n = 0; n < 4; ++n)
          H16[(size_t)row * HC + (bn16 + n) * 16 + cl] = f2bf(acc[m][n][r]);
      }
    }
  }
  // ---- fused att dots: this block covers exactly head `by` (128 cols) ----
  float as_v[4], ad_v[4];
#pragma unroll
  for (int n = 0; n < 4; ++n) {
    const int c = head * CHAN + wc * 64 + n * 16 + cl;
    as_v[n] = att_s[c];
    ad_v[n] = att_d[c];
  }
  __shared__ float red[2][2][2][64];   // [s/d][wc][wr][row_local]
#pragma unroll
  for (int m = 0; m < 4; ++m) {
#pragma unroll
    for (int r = 0; r < 4; ++r) {
      float ps = 0.f, pd = 0.f;
#pragma unroll
      for (int n = 0; n < 4; ++n) { ps += acc[m][n][r] * as_v[n]; pd += acc[m][n][r] * ad_v[n]; }
#pragma unroll
      for (int mask = 1; mask <= 8; mask <<= 1) {
        ps += __shfl_xor(ps, mask); pd += __shfl_xor(pd, mask);
      }
      if (cl == 0) {
        const int rl = m * 16 + rbase + r;
        red[0][wc][wr][rl] = ps;
        red[1][wc][wr][rl] = pd;
      }
    }
  }
  __syncthreads();
  if (tid < 128) {
    const int row = blockIdx.x * 128 + tid;
    if (row < N_NODES) {
      const int wr2 = tid >> 6, rl = tid & 63;
      a_src[row * 4 + head] = red[0][0][wr2][rl] + red[0][1][wr2][rl];
      a_dst[row * 4 + head] = red[1][0][wr2][rl] + red[1][1][wr2][rl];
    }
  }
}

// ---- fused scatter + alpha: CSR position + leaky-relu'd alpha written in CSR order ----
__global__ void scatter_alpha_kernel(const int* __restrict__ EI, const float* __restrict__ EA,
                                     const int* __restrict__ rowstart, int* __restrict__ cnt,
                                     const float* __restrict__ a_src, const float* __restrict__ a_dst,
                                     const float* __restrict__ msum, const float* __restrict__ q,
                                     int* __restrict__ csr_src, float* __restrict__ alphacsr) {
  const int k = blockIdx.x * blockDim.x + threadIdx.x;
  if (k >= TOT_E) return;
  int s, d, pos;
  float e0, e1, e2, e3;
  if (k < N_EDGES) {
    s = EI[k]; d = EI[N_EDGES + k];
    const float4 e = *(const float4*)&EA[(size_t)k * 4];
    e0 = e.x; e1 = e.y; e2 = e.z; e3 = e.w;
    pos = rowstart[d] + atomicAdd(&cnt[d], 1);
    csr_src[pos] = s;
  } else {
    s = d = k - N_EDGES;
    const float inv = 1.0f / (float)N_EDGES;
    e0 = msum[0] * inv; e1 = msum[1] * inv; e2 = msum[2] * inv; e3 = msum[3] * inv;
    pos = k;                       // self region: identity
  }
  const float4 as = *(const float4*)&a_src[s * 4];
  const float4 ad = *(const float4*)&a_dst[d * 4];
  const float asv[4] = {as.x, as.y, as.z, as.w};
  const float adv[4] = {ad.x, ad.y, ad.z, ad.w};
  float al[4];
#pragma unroll
  for (int h = 0; h < 4; ++h) {
    float ae = e0 * q[h] + e1 * q[4 + h] + e2 * q[8 + h] + e3 * q[12 + h];
    float a = asv[h] + adv[h] + ae;
    al[h] = (a >= 0.f) ? a : NEG_SLOPE * a;
  }
  float4 o = {al[0], al[1], al[2], al[3]};
  *(float4*)&alphacsr[(size_t)pos * 4] = o;
}

// ---- per-(node,head) softmax over CSR range; head-major weights out ----
__global__ void softmax_kernel(const int* __restrict__ rowstart,
                               const float* __restrict__ alphacsr,
                               float* __restrict__ w_h) {
  const int tid = blockIdx.x * blockDim.x + threadIdx.x;
  if (tid >= N_NODES * NHEAD) return;
  const int n = tid >> 2, h = tid & 3;
  const int beg = rowstart[n], end = rowstart[n + 1];
  const float aself = alphacsr[(size_t)(N_EDGES + n) * 4 + h];
  float m = aself;
  for (int p = beg; p < end; ++p) m = fmaxf(m, alphacsr[(size_t)p * 4 + h]);
  float den = __expf(aself - m);
  for (int p = beg; p < end; ++p) den += __expf(alphacsr[(size_t)p * 4 + h] - m);
  const float dinv = 1.0f / (den + 1e-16f);
  float* __restrict__ wd = w_h + (size_t)h * TOT_E;
  for (int p = beg; p < end; ++p) wd[p] = __expf(alphacsr[(size_t)p * 4 + h] - m) * dinv;
  wd[N_EDGES + n] = __expf(aself - m) * dinv;
}

// ---- CSR gather-aggregate on bf16 h rows; f32 accumulate; no atomics ----
__global__ __launch_bounds__(128) void csr_aggregate16_kernel(
    const int* __restrict__ rowstart, const int* __restrict__ csr_src,
    const unsigned short* __restrict__ H16, const float* __restrict__ w_h,
    float* __restrict__ out) {
  const int n = blockIdx.x;
  const int t = threadIdx.x;            // 128 threads -> 4 channels each
  const int head = t >> 5;
  const int j = t * 4;
  const float* __restrict__ wd = w_h + (size_t)head * TOT_E;
  const float wself = wd[N_EDGES + n];
  const u16x4 hv = *(const u16x4*)&H16[(size_t)n * HC + j];
  float4 acc = {wself * bf2f(hv.x), wself * bf2f(hv.y),
                wself * bf2f(hv.z), wself * bf2f(hv.w)};
  const int beg = rowstart[n], end = rowstart[n + 1];
  int s_nxt = 0;
  if (beg < end) s_nxt = csr_src[beg];
  for (int idx = beg; idx < end; ++idx) {
    const int s = s_nxt;
    if (idx + 1 < end) s_nxt = csr_src[idx + 1];
    const float w = wd[idx];
    const u16x4 v = *(const u16x4*)&H16[(size_t)s * HC + j];
    acc.x += w * bf2f(v.x); acc.y += w * bf2f(v.y);
    acc.z += w * bf2f(v.z); acc.w += w * bf2f(v.w);
  }
  *(float4*)&out[(size_t)n * HC + j] = acc;
}

// ---- BN column sums / sums of squares ----
__global__ void bn_stats_kernel(const float* __restrict__ out,
                                float* __restrict__ colsum, float* __restrict__ colsq) {
  const int t = threadIdx.x;          // 256 threads -> 2 channels each
  const int j = t * 2;
  float s0 = 0.f, s1 = 0.f, q0 = 0.f, q1 = 0.f;
  for (int r = blockIdx.x; r < N_NODES; r += gridDim.x) {
    const float2 v = *(const float2*)&out[(size_t)r * HC + j];
    s0 += v.x; s1 += v.y; q0 += v.x * v.x; q1 += v.y * v.y;
  }
  atomicAdd(&colsum[j], s0);
  atomicAdd(&colsum[j + 1], s1);
  atomicAdd(&colsq[j], q0);
  atomicAdd(&colsq[j + 1], q1);
}

// ---- BN normalize (per-channel scale/shift computed inline; bias cancels) ----
__global__ void bn_apply_kernel(float* __restrict__ out,
                                const float* __restrict__ colsum, const float* __restrict__ colsq,
                                const float* __restrict__ gamma, const float* __restrict__ beta) {
  const int i = blockIdx.x * blockDim.x + threadIdx.x;   // float4 index
  if (i >= N_NODES * HC / 4) return;
  const int j4 = (i & (HC / 4 - 1)) * 4;
  const float4 cs = *(const float4*)&colsum[j4];
  const float4 cq = *(const float4*)&colsq[j4];
  const float4 g  = *(const float4*)&gamma[j4];
  const float4 b  = *(const float4*)&beta[j4];
  const float inv = 1.0f / N_NODES;
  float4 mu = {cs.x * inv, cs.y * inv, cs.z * inv, cs.w * inv};
  float4 sc, sh;
  sc.x = g.x * rsqrtf(cq.x * inv - mu.x * mu.x + BN_EPS);
  sc.y = g.y * rsqrtf(cq.y * inv - mu.y * mu.y + BN_EPS);
  sc.z = g.z * rsqrtf(cq.z * inv - mu.z * mu.z + BN_EPS);
  sc.w = g.w * rsqrtf(cq.w * inv - mu.w * mu.w + BN_EPS);
  sh.x = b.x - mu.x * sc.x; sh.y = b.y - mu.y * sc.y;
  sh.z = b.z - mu.z * sc.z; sh.w = b.w - mu.w * sc.w;
  float4 v = ((const float4*)out)[i];
  v.x = v.x * sc.x + sh.x; v.y = v.y * sc.y + sh.y;
  v.z = v.z * sc.z + sh.z; v.w = v.w * sc.w + sh.w;
  ((float4*)out)[i] = v;
}

extern "C" void kernel_launch(void* const* d_in, const int* in_sizes, int n_in,
                              void* d_out, int out_size, void* d_ws, size_t ws_size,
                              hipStream_t stream) {
  const float* x     = (const float*)d_in[0];
  const int*   ei    = (const int*)d_in[1];
  const float* ea    = (const float*)d_in[2];
  const float* W     = (const float*)d_in[3];
  const float* We    = (const float*)d_in[4];
  const float* att_s = (const float*)d_in[5];
  const float* att_d = (const float*)d_in[6];
  const float* att_e = (const float*)d_in[7];
  // d_in[8] = bias: cancels exactly in BatchNorm -> unused
  const float* gamma = (const float*)d_in[9];
  const float* beta  = (const float*)d_in[10];
  float* out = (float*)d_out;
  float* ws  = (float*)d_ws;

  // workspace layout
  unsigned short* H16     = (unsigned short*)ws;                   // N*512 bf16
  float*    a_src   = (float*)(H16 + (size_t)N_NODES * HC);        // N*4
  float*    a_dst   = a_src + N_NODES * NHEAD;                     // N*4
  float*    alphacsr= a_dst + N_NODES * NHEAD;                     // TOT_E*4
  float*    w_h     = alphacsr + (size_t)TOT_E * NHEAD;            // 4*TOT_E (head-major)
  float*    qm      = w_h + (size_t)NHEAD * TOT_E;                 // 16
  int*      rowstart= (int*)(qm + 16);                             // N+1 (pad 20004)
  int*      csr_src = rowstart + 20004;                            // E
  unsigned short* Ap = (unsigned short*)(csr_src + N_EDGES);       // M16_PAD*16*64*8
  unsigned short* Bp = Ap + (size_t)M16_PAD * 16 * 64 * 8;         // 32*16*64*8
  // ---- zeroed-every-call block ----
  int*      deg     = (int*)(Bp + 32 * 16 * 64 * 8);               // N
  int*      cnt     = deg + N_NODES;                               // N
  float*    msum    = (float*)(cnt + N_NODES);                     // 4
  float*    colsum  = msum + 4;                                    // 512
  float*    colsq   = colsum + HC;                                 // 512

  const size_t zero_bytes = (size_t)(N_NODES * 2 + 4 + HC * 2) * sizeof(float);
  hipMemsetAsync(deg, 0, zero_bytes, stream);

  prep_kernel<<<256, 256, 0, stream>>>(ea, ei, We, att_e, msum, deg, qm);
  scan_kernel<<<1, 1024, 0, stream>>>(deg, rowstart);
  pack_ab_kernel<<<128 + M16_PAD * 16 * 64 / 256, 256, 0, stream>>>(x, W, Ap, Bp);
  mfma_gemm_fused<<<dim3(157, 4), 256, 0, stream>>>(Ap, Bp, att_s, att_d, H16, a_src, a_dst);
  scatter_alpha_kernel<<<(TOT_E + 255) / 256, 256, 0, stream>>>(ei, ea, rowstart, cnt,
                                                                a_src, a_dst, msum, qm,
                                                                csr_src, alphacsr);
  softmax_kernel<<<(N_NODES * NHEAD + 255) / 256, 256, 0, stream>>>(rowstart, alphacsr, w_h);
  csr_aggregate16_kernel<<<N_NODES, 128, 0, stream>>>(rowstart, csr_src, H16, w_h, out);
  bn_stats_kernel<<<256, 256, 0, stream>>>(out, colsum, colsq);
  bn_apply_kernel<<<(N_NODES * HC / 4 + 255) / 256, 256, 0, stream>>>(out, colsum, colsq,
                                                                     gamma, beta);
}

// Round 6
// 213.928 us; speedup vs baseline: 11.8819x; 1.0999x over previous
//
#include <hip/hip_runtime.h>
#include <math.h>

#define N_NODES 20000
#define N_EDGES 320000
#define TOT_E   340000      // E + N self loops
#define IN_F    512
#define HC      512         // H*C
#define NHEAD   4
#define CHAN    128
#define NEG_SLOPE 0.2f
#define BN_EPS  1e-5f

#define M16_PAD 1256        // 157 row-blocks * 8 = padded count of 16-row fragments
#define PACK_BLOCKS (128 + M16_PAD * 16 * 64 / 256)   // 5152
#define PREP_BLOCKS 256

typedef short short8v __attribute__((ext_vector_type(8)));   // 8 bf16 (4 VGPRs)
typedef float f32x4  __attribute__((ext_vector_type(4)));
typedef unsigned short u16x8 __attribute__((ext_vector_type(8)));

// ---- f32 -> bf16 bits, round-to-nearest-even ----
__device__ __forceinline__ unsigned short f2bf(float f) {
  unsigned u = __float_as_uint(f);
  return (unsigned short)((u + 0x7FFFu + ((u >> 16) & 1u)) >> 16);
}
__device__ __forceinline__ float bf2f(unsigned short b) {
  return __uint_as_float(((unsigned)b) << 16);
}

// ---- fused: pack A/B fragments (blocks 0..PACK_BLOCKS) + prep (histogram,
//      edge-attr colsums, qmat) on the trailing PREP_BLOCKS blocks ----
__global__ void prep_pack_kernel(const float* __restrict__ X, const float* __restrict__ W,
                                 unsigned short* __restrict__ Ap, unsigned short* __restrict__ Bp,
                                 const float* __restrict__ EA, const int* __restrict__ EI,
                                 const float* __restrict__ We, const float* __restrict__ aedg,
                                 float* __restrict__ msum, int* __restrict__ deg,
                                 float* __restrict__ qm) {
  if (blockIdx.x < 128) {
    // pack B: Bp[((n16*16 + k32)*64 + l)*8 + j] = W[k32*32+(l>>4)*8+j][n16*16+(l&15)]
    const int tid = blockIdx.x * blockDim.x + threadIdx.x;   // 32768
    const int l = tid & 63;
    const int k32 = (tid >> 6) & 15;
    const int n16 = tid >> 10;
    const int col = n16 * 16 + (l & 15);
    const int k = k32 * 32 + ((l >> 4) << 3);
    unsigned short v[8];
#pragma unroll
    for (int j = 0; j < 8; ++j) v[j] = f2bf(W[(size_t)(k + j) * HC + col]);
    *(short8v*)&Bp[(size_t)tid * 8] = *(short8v*)v;
  } else if (blockIdx.x < PACK_BLOCKS) {
    // pack A: Ap[((m16*16 + k32)*64 + l)*8 + j] = x[m16*16+(l&15)][k32*32+(l>>4)*8+j]
    const int tid = (blockIdx.x - 128) * blockDim.x + threadIdx.x; // M16_PAD*16*64
    const int l = tid & 63;
    const int k32 = (tid >> 6) & 15;
    const int m16 = tid >> 10;
    const int row = m16 * 16 + (l & 15);
    const int k = k32 * 32 + ((l >> 4) << 3);
    unsigned short v[8] = {0, 0, 0, 0, 0, 0, 0, 0};
    if (row < N_NODES) {
      const float4 f0 = *(const float4*)&X[(size_t)row * IN_F + k];
      const float4 f1 = *(const float4*)&X[(size_t)row * IN_F + k + 4];
      v[0] = f2bf(f0.x); v[1] = f2bf(f0.y); v[2] = f2bf(f0.z); v[3] = f2bf(f0.w);
      v[4] = f2bf(f1.x); v[5] = f2bf(f1.y); v[6] = f2bf(f1.z); v[7] = f2bf(f1.w);
    }
    *(short8v*)&Ap[(size_t)tid * 8] = *(short8v*)v;
  } else {
    const int bid = blockIdx.x - PACK_BLOCKS;    // 0..255
    // qmat: q[d][h] = sum_c W_edge[d, h*C+c] * att_edge[h, c]
    if (bid < 16 && threadIdx.x < 64) {
      const int d = bid >> 2, h = bid & 3, lane = threadIdx.x;
      const int base = h * CHAN + lane * 2;
      float v = We[d * HC + base] * aedg[base] + We[d * HC + base + 1] * aedg[base + 1];
#pragma unroll
      for (int m = 32; m >= 1; m >>= 1) v += __shfl_down(v, m);
      if (lane == 0) qm[d * 4 + h] = v;
    }
    float s0 = 0.f, s1 = 0.f, s2 = 0.f, s3 = 0.f;
    for (int i = bid * blockDim.x + threadIdx.x; i < N_EDGES;
         i += PREP_BLOCKS * blockDim.x) {
      const float4 v = *(const float4*)&EA[(size_t)i * 4];
      s0 += v.x; s1 += v.y; s2 += v.z; s3 += v.w;
      atomicAdd(&deg[EI[N_EDGES + i]], 1);
    }
#pragma unroll
    for (int m = 32; m >= 1; m >>= 1) {
      s0 += __shfl_down(s0, m); s1 += __shfl_down(s1, m);
      s2 += __shfl_down(s2, m); s3 += __shfl_down(s3, m);
    }
    __shared__ float red[4][4];
    const int lane = threadIdx.x & 63, wid = threadIdx.x >> 6;
    if (lane == 0) { red[wid][0] = s0; red[wid][1] = s1; red[wid][2] = s2; red[wid][3] = s3; }
    __syncthreads();
    if (threadIdx.x < 4) {
      float v = red[0][threadIdx.x] + red[1][threadIdx.x] + red[2][threadIdx.x] + red[3][threadIdx.x];
      atomicAdd(&msum[threadIdx.x], v);
    }
  }
}

// ---- exclusive prefix sum over deg[20000] -> rowstart[20001]; one block/1024thr ----
__global__ __launch_bounds__(1024) void scan_kernel(const int* __restrict__ deg,
                                                    int* __restrict__ rowstart) {
  __shared__ int part[1024];
  const int t = threadIdx.x;
  const int base = t * 20;
  int local[20];
  int s = 0;
#pragma unroll
  for (int i = 0; i < 20; ++i) {
    const int idx = base + i;
    const int v = (idx < N_NODES) ? deg[idx] : 0;
    local[i] = s;           // exclusive within chunk
    s += v;
  }
  part[t] = s;
  __syncthreads();
  for (int off = 1; off < 1024; off <<= 1) {
    const int v = (t >= off) ? part[t - off] : 0;
    __syncthreads();
    part[t] += v;
    __syncthreads();
  }
  const int excl = (t > 0) ? part[t - 1] : 0;
#pragma unroll
  for (int i = 0; i < 20; ++i) {
    const int idx = base + i;
    if (idx < N_NODES) rowstart[idx] = excl + local[i];
  }
  if (t == 1023) rowstart[N_NODES] = part[1023];
}

// ---- h = x @ W via bf16 MFMA; writes h as bf16; fuses per-head att dots ----
// blockIdx.y == head (128 cols). a_src/a_dst computed exactly (f32 acc).
__global__ __launch_bounds__(256) void mfma_gemm_fused(const unsigned short* __restrict__ Ap_,
                                                       const unsigned short* __restrict__ Bp_,
                                                       const float* __restrict__ att_s,
                                                       const float* __restrict__ att_d,
                                                       unsigned short* __restrict__ H16,
                                                       float* __restrict__ a_src,
                                                       float* __restrict__ a_dst) {
  const short8v* __restrict__ Ap = (const short8v*)Ap_;
  const short8v* __restrict__ Bp = (const short8v*)Bp_;
  const int tid = threadIdx.x;
  const int l = tid & 63;
  const int w = tid >> 6;                 // 4 waves, 2x2
  const int wr = w >> 1, wc = w & 1;
  const int bm16 = blockIdx.x * 8 + wr * 4;   // 16-row fragment base (global)
  const int bn16 = blockIdx.y * 8 + wc * 4;   // 16-col fragment base
  const int head = blockIdx.y;
  f32x4 acc[4][4] = {};
#pragma unroll 2
  for (int kk = 0; kk < IN_F / 32; ++kk) {
    short8v a[4], b[4];
#pragma unroll
    for (int m = 0; m < 4; ++m) a[m] = Ap[((size_t)(bm16 + m) * 16 + kk) * 64 + l];
#pragma unroll
    for (int n = 0; n < 4; ++n) b[n] = Bp[((size_t)(bn16 + n) * 16 + kk) * 64 + l];
#pragma unroll
    for (int m = 0; m < 4; ++m)
#pragma unroll
      for (int n = 0; n < 4; ++n)
        acc[m][n] = __builtin_amdgcn_mfma_f32_16x16x32_bf16(a[m], b[n], acc[m][n], 0, 0, 0);
  }
  const int rbase = (l >> 4) * 4;   // C/D: col = l&15, row = (l>>4)*4 + r
  const int cl = l & 15;
  // ---- store h in bf16 ----
#pragma unroll
  for (int m = 0; m < 4; ++m) {
#pragma unroll
    for (int r = 0; r < 4; ++r) {
      const int row = (bm16 + m) * 16 + rbase + r;
      if (row < N_NODES) {
#pragma unroll
        for (int n = 0; n < 4; ++n)
          H16[(size_t)row * HC + (bn16 + n) * 16 + cl] = f2bf(acc[m][n][r]);
      }
    }
  }
  // ---- fused att dots: this block covers exactly head `blockIdx.y` ----
  float as_v[4], ad_v[4];
#pragma unroll
  for (int n = 0; n < 4; ++n) {
    const int c = head * CHAN + wc * 64 + n * 16 + cl;
    as_v[n] = att_s[c];
    ad_v[n] = att_d[c];
  }
  __shared__ float red[2][2][2][64];   // [s/d][wc][wr][row_local]
#pragma unroll
  for (int m = 0; m < 4; ++m) {
#pragma unroll
    for (int r = 0; r < 4; ++r) {
      float ps = 0.f, pd = 0.f;
#pragma unroll
      for (int n = 0; n < 4; ++n) { ps += acc[m][n][r] * as_v[n]; pd += acc[m][n][r] * ad_v[n]; }
#pragma unroll
      for (int mask = 1; mask <= 8; mask <<= 1) {
        ps += __shfl_xor(ps, mask); pd += __shfl_xor(pd, mask);
      }
      if (cl == 0) {
        const int rl = m * 16 + rbase + r;
        red[0][wc][wr][rl] = ps;
        red[1][wc][wr][rl] = pd;
      }
    }
  }
  __syncthreads();
  if (tid < 128) {
    const int row = blockIdx.x * 128 + tid;
    if (row < N_NODES) {
      const int wr2 = tid >> 6, rl = tid & 63;
      a_src[row * 4 + head] = red[0][0][wr2][rl] + red[0][1][wr2][rl];
      a_dst[row * 4 + head] = red[1][0][wr2][rl] + red[1][1][wr2][rl];
    }
  }
}

// ---- fused scatter + alpha: CSR position + leaky-relu'd alpha written in CSR order ----
__global__ void scatter_alpha_kernel(const int* __restrict__ EI, const float* __restrict__ EA,
                                     const int* __restrict__ rowstart, int* __restrict__ cnt,
                                     const float* __restrict__ a_src, const float* __restrict__ a_dst,
                                     const float* __restrict__ msum, const float* __restrict__ q,
                                     int* __restrict__ csr_src, float* __restrict__ alphacsr) {
  const int k = blockIdx.x * blockDim.x + threadIdx.x;
  if (k >= TOT_E) return;
  int s, d, pos;
  float e0, e1, e2, e3;
  if (k < N_EDGES) {
    s = EI[k]; d = EI[N_EDGES + k];
    const float4 e = *(const float4*)&EA[(size_t)k * 4];
    e0 = e.x; e1 = e.y; e2 = e.z; e3 = e.w;
    pos = rowstart[d] + atomicAdd(&cnt[d], 1);
    csr_src[pos] = s;
  } else {
    s = d = k - N_EDGES;
    const float inv = 1.0f / (float)N_EDGES;
    e0 = msum[0] * inv; e1 = msum[1] * inv; e2 = msum[2] * inv; e3 = msum[3] * inv;
    pos = k;                       // self region: identity
  }
  const float4 as = *(const float4*)&a_src[s * 4];
  const float4 ad = *(const float4*)&a_dst[d * 4];
  const float asv[4] = {as.x, as.y, as.z, as.w};
  const float adv[4] = {ad.x, ad.y, ad.z, ad.w};
  float al[4];
#pragma unroll
  for (int h = 0; h < 4; ++h) {
    float ae = e0 * q[h] + e1 * q[4 + h] + e2 * q[8 + h] + e3 * q[12 + h];
    float a = asv[h] + adv[h] + ae;
    al[h] = (a >= 0.f) ? a : NEG_SLOPE * a;
  }
  float4 o = {al[0], al[1], al[2], al[3]};
  *(float4*)&alphacsr[(size_t)pos * 4] = o;
}

// ---- fused softmax + CSR gather-aggregate: one WAVE per node, no atomics ----
// lane l: channels l*8..l*8+7 (16B bf16 loads); head = l>>4; 16 lanes per head.
__global__ __launch_bounds__(256) void agg_fused_kernel(
    const int* __restrict__ rowstart, const int* __restrict__ csr_src,
    const float* __restrict__ alphacsr, const unsigned short* __restrict__ H16,
    float* __restrict__ out) {
  const int wid = threadIdx.x >> 6;
  const int n = blockIdx.x * 4 + wid;           // grid 5000 * 4 waves = 20000
  const int l = threadIdx.x & 63;
  const int head = l >> 4;
  const int j = l * 8;
  const int lo = l & 15;                        // lane within head group
  const int beg = rowstart[n], end = rowstart[n + 1];
  const float aself = alphacsr[(size_t)(N_EDGES + n) * 4 + head];
  // pass 1: per-head max (16-lane strided walk + butterfly)
  float m = aself;
  for (int p = beg + lo; p < end; p += 16)
    m = fmaxf(m, alphacsr[(size_t)p * 4 + head]);
#pragma unroll
  for (int mask = 1; mask <= 8; mask <<= 1) m = fmaxf(m, __shfl_xor(m, mask));
  // pass 2: denominator
  float den = 0.f;
  for (int p = beg + lo; p < end; p += 16)
    den += __expf(alphacsr[(size_t)p * 4 + head] - m);
#pragma unroll
  for (int mask = 1; mask <= 8; mask <<= 1) den += __shfl_xor(den, mask);
  den += __expf(aself - m);
  const float dinv = 1.0f / (den + 1e-16f);
  // pass 3: weighted gather (weights recomputed inline; broadcast loads)
  const float wself = __expf(aself - m) * dinv;
  const u16x8 hv = *(const u16x8*)&H16[(size_t)n * HC + j];
  float acc[8];
#pragma unroll
  for (int c = 0; c < 8; ++c) acc[c] = wself * bf2f(hv[c]);
  int s_nxt = 0;
  if (beg < end) s_nxt = csr_src[beg];
  for (int idx = beg; idx < end; ++idx) {
    const int s = s_nxt;
    if (idx + 1 < end) s_nxt = csr_src[idx + 1];
    const float w = __expf(alphacsr[(size_t)idx * 4 + head] - m) * dinv;
    const u16x8 v = *(const u16x8*)&H16[(size_t)s * HC + j];
#pragma unroll
    for (int c = 0; c < 8; ++c) acc[c] += w * bf2f(v[c]);
  }
  float4 o0 = {acc[0], acc[1], acc[2], acc[3]};
  float4 o1 = {acc[4], acc[5], acc[6], acc[7]};
  *(float4*)&out[(size_t)n * HC + j] = o0;
  *(float4*)&out[(size_t)n * HC + j + 4] = o1;
}

// ---- BN column sums / sums of squares ----
__global__ void bn_stats_kernel(const float* __restrict__ out,
                                float* __restrict__ colsum, float* __restrict__ colsq) {
  const int t = threadIdx.x;          // 256 threads -> 2 channels each
  const int j = t * 2;
  float s0 = 0.f, s1 = 0.f, q0 = 0.f, q1 = 0.f;
  for (int r = blockIdx.x; r < N_NODES; r += gridDim.x) {
    const float2 v = *(const float2*)&out[(size_t)r * HC + j];
    s0 += v.x; s1 += v.y; q0 += v.x * v.x; q1 += v.y * v.y;
  }
  atomicAdd(&colsum[j], s0);
  atomicAdd(&colsum[j + 1], s1);
  atomicAdd(&colsq[j], q0);
  atomicAdd(&colsq[j + 1], q1);
}

// ---- BN normalize (per-channel scale/shift computed inline; bias cancels) ----
__global__ void bn_apply_kernel(float* __restrict__ out,
                                const float* __restrict__ colsum, const float* __restrict__ colsq,
                                const float* __restrict__ gamma, const float* __restrict__ beta) {
  const int i = blockIdx.x * blockDim.x + threadIdx.x;   // float4 index
  if (i >= N_NODES * HC / 4) return;
  const int j4 = (i & (HC / 4 - 1)) * 4;
  const float4 cs = *(const float4*)&colsum[j4];
  const float4 cq = *(const float4*)&colsq[j4];
  const float4 g  = *(const float4*)&gamma[j4];
  const float4 b  = *(const float4*)&beta[j4];
  const float inv = 1.0f / N_NODES;
  float4 mu = {cs.x * inv, cs.y * inv, cs.z * inv, cs.w * inv};
  float4 sc, sh;
  sc.x = g.x * rsqrtf(cq.x * inv - mu.x * mu.x + BN_EPS);
  sc.y = g.y * rsqrtf(cq.y * inv - mu.y * mu.y + BN_EPS);
  sc.z = g.z * rsqrtf(cq.z * inv - mu.z * mu.z + BN_EPS);
  sc.w = g.w * rsqrtf(cq.w * inv - mu.w * mu.w + BN_EPS);
  sh.x = b.x - mu.x * sc.x; sh.y = b.y - mu.y * sc.y;
  sh.z = b.z - mu.z * sc.z; sh.w = b.w - mu.w * sc.w;
  float4 v = ((const float4*)out)[i];
  v.x = v.x * sc.x + sh.x; v.y = v.y * sc.y + sh.y;
  v.z = v.z * sc.z + sh.z; v.w = v.w * sc.w + sh.w;
  ((float4*)out)[i] = v;
}

extern "C" void kernel_launch(void* const* d_in, const int* in_sizes, int n_in,
                              void* d_out, int out_size, void* d_ws, size_t ws_size,
                              hipStream_t stream) {
  const float* x     = (const float*)d_in[0];
  const int*   ei    = (const int*)d_in[1];
  const float* ea    = (const float*)d_in[2];
  const float* W     = (const float*)d_in[3];
  const float* We    = (const float*)d_in[4];
  const float* att_s = (const float*)d_in[5];
  const float* att_d = (const float*)d_in[6];
  const float* att_e = (const float*)d_in[7];
  // d_in[8] = bias: cancels exactly in BatchNorm -> unused
  const float* gamma = (const float*)d_in[9];
  const float* beta  = (const float*)d_in[10];
  float* out = (float*)d_out;
  float* ws  = (float*)d_ws;

  // workspace layout
  unsigned short* H16     = (unsigned short*)ws;                   // N*512 bf16
  float*    a_src   = (float*)(H16 + (size_t)N_NODES * HC);        // N*4
  float*    a_dst   = a_src + N_NODES * NHEAD;                     // N*4
  float*    alphacsr= a_dst + N_NODES * NHEAD;                     // TOT_E*4
  float*    qm      = alphacsr + (size_t)TOT_E * NHEAD;            // 16
  int*      rowstart= (int*)(qm + 16);                             // N+1 (pad 20004)
  int*      csr_src = rowstart + 20004;                            // E
  unsigned short* Ap = (unsigned short*)(csr_src + N_EDGES);       // M16_PAD*16*64*8
  unsigned short* Bp = Ap + (size_t)M16_PAD * 16 * 64 * 8;         // 32*16*64*8
  // ---- zeroed-every-call block ----
  int*      deg     = (int*)(Bp + 32 * 16 * 64 * 8);               // N
  int*      cnt     = deg + N_NODES;                               // N
  float*    msum    = (float*)(cnt + N_NODES);                     // 4
  float*    colsum  = msum + 4;                                    // 512
  float*    colsq   = colsum + HC;                                 // 512

  const size_t zero_bytes = (size_t)(N_NODES * 2 + 4 + HC * 2) * sizeof(float);
  hipMemsetAsync(deg, 0, zero_bytes, stream);

  prep_pack_kernel<<<PACK_BLOCKS + PREP_BLOCKS, 256, 0, stream>>>(
      x, W, Ap, Bp, ea, ei, We, att_e, msum, deg, qm);
  scan_kernel<<<1, 1024, 0, stream>>>(deg, rowstart);
  mfma_gemm_fused<<<dim3(157, 4), 256, 0, stream>>>(Ap, Bp, att_s, att_d, H16, a_src, a_dst);
  scatter_alpha_kernel<<<(TOT_E + 255) / 256, 256, 0, stream>>>(ei, ea, rowstart, cnt,
                                                                a_src, a_dst, msum, qm,
                                                                csr_src, alphacsr);
  agg_fused_kernel<<<N_NODES / 4, 256, 0, stream>>>(rowstart, csr_src, alphacsr, H16, out);
  bn_stats_kernel<<<256, 256, 0, stream>>>(out, colsum, colsq);
  bn_apply_kernel<<<(N_NODES * HC / 4 + 255) / 256, 256, 0, stream>>>(out, colsum, colsq,
                                                                     gamma, beta);
}

// Round 7
// 187.059 us; speedup vs baseline: 13.5886x; 1.1436x over previous
//
#include <hip/hip_runtime.h>
#include <math.h>

#define N_NODES 20000
#define N_EDGES 320000
#define TOT_E   340000      // E + N self loops
#define IN_F    512
#define HC      512         // H*C
#define NHEAD   4
#define CHAN    128
#define NEG_SLOPE 0.2f
#define BN_EPS  1e-5f
#define NSLICE  32          // BN partial-stat contention slices

#define M16_PAD 1256        // 157 row-blocks * 8 = padded count of 16-row fragments
#define PACK_BLOCKS (128 + M16_PAD * 16 * 64 / 256)   // 5152
#define PREP_BLOCKS 256

typedef short short8v __attribute__((ext_vector_type(8)));   // 8 bf16 (4 VGPRs)
typedef float f32x4  __attribute__((ext_vector_type(4)));
typedef unsigned short u16x8 __attribute__((ext_vector_type(8)));

// ---- f32 -> bf16 bits, round-to-nearest-even ----
__device__ __forceinline__ unsigned short f2bf(float f) {
  unsigned u = __float_as_uint(f);
  return (unsigned short)((u + 0x7FFFu + ((u >> 16) & 1u)) >> 16);
}
__device__ __forceinline__ float bf2f(unsigned short b) {
  return __uint_as_float(((unsigned)b) << 16);
}

// ---- fused: pack A/B fragments (blocks 0..PACK_BLOCKS) + prep (histogram,
//      edge-attr colsums, qmat) on the trailing PREP_BLOCKS blocks ----
__global__ void prep_pack_kernel(const float* __restrict__ X, const float* __restrict__ W,
                                 unsigned short* __restrict__ Ap, unsigned short* __restrict__ Bp,
                                 const float* __restrict__ EA, const int* __restrict__ EI,
                                 const float* __restrict__ We, const float* __restrict__ aedg,
                                 float* __restrict__ msum, int* __restrict__ deg,
                                 float* __restrict__ qm) {
  if (blockIdx.x < 128) {
    // pack B: Bp[((n16*16 + k32)*64 + l)*8 + j] = W[k32*32+(l>>4)*8+j][n16*16+(l&15)]
    const int tid = blockIdx.x * blockDim.x + threadIdx.x;   // 32768
    const int l = tid & 63;
    const int k32 = (tid >> 6) & 15;
    const int n16 = tid >> 10;
    const int col = n16 * 16 + (l & 15);
    const int k = k32 * 32 + ((l >> 4) << 3);
    unsigned short v[8];
#pragma unroll
    for (int j = 0; j < 8; ++j) v[j] = f2bf(W[(size_t)(k + j) * HC + col]);
    *(short8v*)&Bp[(size_t)tid * 8] = *(short8v*)v;
  } else if (blockIdx.x < PACK_BLOCKS) {
    // pack A: Ap[((m16*16 + k32)*64 + l)*8 + j] = x[m16*16+(l&15)][k32*32+(l>>4)*8+j]
    const int tid = (blockIdx.x - 128) * blockDim.x + threadIdx.x; // M16_PAD*16*64
    const int l = tid & 63;
    const int k32 = (tid >> 6) & 15;
    const int m16 = tid >> 10;
    const int row = m16 * 16 + (l & 15);
    const int k = k32 * 32 + ((l >> 4) << 3);
    unsigned short v[8] = {0, 0, 0, 0, 0, 0, 0, 0};
    if (row < N_NODES) {
      const float4 f0 = *(const float4*)&X[(size_t)row * IN_F + k];
      const float4 f1 = *(const float4*)&X[(size_t)row * IN_F + k + 4];
      v[0] = f2bf(f0.x); v[1] = f2bf(f0.y); v[2] = f2bf(f0.z); v[3] = f2bf(f0.w);
      v[4] = f2bf(f1.x); v[5] = f2bf(f1.y); v[6] = f2bf(f1.z); v[7] = f2bf(f1.w);
    }
    *(short8v*)&Ap[(size_t)tid * 8] = *(short8v*)v;
  } else {
    const int bid = blockIdx.x - PACK_BLOCKS;    // 0..255
    // qmat: q[d][h] = sum_c W_edge[d, h*C+c] * att_edge[h, c]
    if (bid < 16 && threadIdx.x < 64) {
      const int d = bid >> 2, h = bid & 3, lane = threadIdx.x;
      const int base = h * CHAN + lane * 2;
      float v = We[d * HC + base] * aedg[base] + We[d * HC + base + 1] * aedg[base + 1];
#pragma unroll
      for (int m = 32; m >= 1; m >>= 1) v += __shfl_down(v, m);
      if (lane == 0) qm[d * 4 + h] = v;
    }
    float s0 = 0.f, s1 = 0.f, s2 = 0.f, s3 = 0.f;
    for (int i = bid * blockDim.x + threadIdx.x; i < N_EDGES;
         i += PREP_BLOCKS * blockDim.x) {
      const float4 v = *(const float4*)&EA[(size_t)i * 4];
      s0 += v.x; s1 += v.y; s2 += v.z; s3 += v.w;
      atomicAdd(&deg[EI[N_EDGES + i]], 1);
    }
#pragma unroll
    for (int m = 32; m >= 1; m >>= 1) {
      s0 += __shfl_down(s0, m); s1 += __shfl_down(s1, m);
      s2 += __shfl_down(s2, m); s3 += __shfl_down(s3, m);
    }
    __shared__ float red[4][4];
    const int lane = threadIdx.x & 63, wid = threadIdx.x >> 6;
    if (lane == 0) { red[wid][0] = s0; red[wid][1] = s1; red[wid][2] = s2; red[wid][3] = s3; }
    __syncthreads();
    if (threadIdx.x < 4) {
      float v = red[0][threadIdx.x] + red[1][threadIdx.x] + red[2][threadIdx.x] + red[3][threadIdx.x];
      atomicAdd(&msum[threadIdx.x], v);
    }
  }
}

// ---- exclusive prefix sum over deg[20000] -> rowstart[20001]; one block/1024thr ----
__global__ __launch_bounds__(1024) void scan_kernel(const int* __restrict__ deg,
                                                    int* __restrict__ rowstart) {
  __shared__ int part[1024];
  const int t = threadIdx.x;
  const int base = t * 20;
  int local[20];
  int s = 0;
#pragma unroll
  for (int i = 0; i < 20; ++i) {
    const int idx = base + i;
    const int v = (idx < N_NODES) ? deg[idx] : 0;
    local[i] = s;           // exclusive within chunk
    s += v;
  }
  part[t] = s;
  __syncthreads();
  for (int off = 1; off < 1024; off <<= 1) {
    const int v = (t >= off) ? part[t - off] : 0;
    __syncthreads();
    part[t] += v;
    __syncthreads();
  }
  const int excl = (t > 0) ? part[t - 1] : 0;
#pragma unroll
  for (int i = 0; i < 20; ++i) {
    const int idx = base + i;
    if (idx < N_NODES) rowstart[idx] = excl + local[i];
  }
  if (t == 1023) rowstart[N_NODES] = part[1023];
}

// ---- h = x @ W via bf16 MFMA; writes h as bf16; fuses per-head att dots ----
// blockIdx.y == head (128 cols). a_src/a_dst computed exactly (f32 acc).
__global__ __launch_bounds__(256) void mfma_gemm_fused(const unsigned short* __restrict__ Ap_,
                                                       const unsigned short* __restrict__ Bp_,
                                                       const float* __restrict__ att_s,
                                                       const float* __restrict__ att_d,
                                                       unsigned short* __restrict__ H16,
                                                       float* __restrict__ a_src,
                                                       float* __restrict__ a_dst) {
  const short8v* __restrict__ Ap = (const short8v*)Ap_;
  const short8v* __restrict__ Bp = (const short8v*)Bp_;
  const int tid = threadIdx.x;
  const int l = tid & 63;
  const int w = tid >> 6;                 // 4 waves, 2x2
  const int wr = w >> 1, wc = w & 1;
  const int bm16 = blockIdx.x * 8 + wr * 4;   // 16-row fragment base (global)
  const int bn16 = blockIdx.y * 8 + wc * 4;   // 16-col fragment base
  const int head = blockIdx.y;
  f32x4 acc[4][4] = {};
#pragma unroll 2
  for (int kk = 0; kk < IN_F / 32; ++kk) {
    short8v a[4], b[4];
#pragma unroll
    for (int m = 0; m < 4; ++m) a[m] = Ap[((size_t)(bm16 + m) * 16 + kk) * 64 + l];
#pragma unroll
    for (int n = 0; n < 4; ++n) b[n] = Bp[((size_t)(bn16 + n) * 16 + kk) * 64 + l];
#pragma unroll
    for (int m = 0; m < 4; ++m)
#pragma unroll
      for (int n = 0; n < 4; ++n)
        acc[m][n] = __builtin_amdgcn_mfma_f32_16x16x32_bf16(a[m], b[n], acc[m][n], 0, 0, 0);
  }
  const int rbase = (l >> 4) * 4;   // C/D: col = l&15, row = (l>>4)*4 + r
  const int cl = l & 15;
  // ---- store h in bf16 ----
#pragma unroll
  for (int m = 0; m < 4; ++m) {
#pragma unroll
    for (int r = 0; r < 4; ++r) {
      const int row = (bm16 + m) * 16 + rbase + r;
      if (row < N_NODES) {
#pragma unroll
        for (int n = 0; n < 4; ++n)
          H16[(size_t)row * HC + (bn16 + n) * 16 + cl] = f2bf(acc[m][n][r]);
      }
    }
  }
  // ---- fused att dots: this block covers exactly head `blockIdx.y` ----
  float as_v[4], ad_v[4];
#pragma unroll
  for (int n = 0; n < 4; ++n) {
    const int c = head * CHAN + wc * 64 + n * 16 + cl;
    as_v[n] = att_s[c];
    ad_v[n] = att_d[c];
  }
  __shared__ float red[2][2][2][64];   // [s/d][wc][wr][row_local]
#pragma unroll
  for (int m = 0; m < 4; ++m) {
#pragma unroll
    for (int r = 0; r < 4; ++r) {
      float ps = 0.f, pd = 0.f;
#pragma unroll
      for (int n = 0; n < 4; ++n) { ps += acc[m][n][r] * as_v[n]; pd += acc[m][n][r] * ad_v[n]; }
#pragma unroll
      for (int mask = 1; mask <= 8; mask <<= 1) {
        ps += __shfl_xor(ps, mask); pd += __shfl_xor(pd, mask);
      }
      if (cl == 0) {
        const int rl = m * 16 + rbase + r;
        red[0][wc][wr][rl] = ps;
        red[1][wc][wr][rl] = pd;
      }
    }
  }
  __syncthreads();
  if (tid < 128) {
    const int row = blockIdx.x * 128 + tid;
    if (row < N_NODES) {
      const int wr2 = tid >> 6, rl = tid & 63;
      a_src[row * 4 + head] = red[0][0][wr2][rl] + red[0][1][wr2][rl];
      a_dst[row * 4 + head] = red[1][0][wr2][rl] + red[1][1][wr2][rl];
    }
  }
}

// ---- fused scatter + alpha: CSR position + leaky-relu'd alpha written in CSR order ----
__global__ void scatter_alpha_kernel(const int* __restrict__ EI, const float* __restrict__ EA,
                                     const int* __restrict__ rowstart, int* __restrict__ cnt,
                                     const float* __restrict__ a_src, const float* __restrict__ a_dst,
                                     const float* __restrict__ msum, const float* __restrict__ q,
                                     int* __restrict__ csr_src, float* __restrict__ alphacsr) {
  const int k = blockIdx.x * blockDim.x + threadIdx.x;
  if (k >= TOT_E) return;
  int s, d, pos;
  float e0, e1, e2, e3;
  if (k < N_EDGES) {
    s = EI[k]; d = EI[N_EDGES + k];
    const float4 e = *(const float4*)&EA[(size_t)k * 4];
    e0 = e.x; e1 = e.y; e2 = e.z; e3 = e.w;
    pos = rowstart[d] + atomicAdd(&cnt[d], 1);
    csr_src[pos] = s;
  } else {
    s = d = k - N_EDGES;
    const float inv = 1.0f / (float)N_EDGES;
    e0 = msum[0] * inv; e1 = msum[1] * inv; e2 = msum[2] * inv; e3 = msum[3] * inv;
    pos = k;                       // self region: identity
  }
  const float4 as = *(const float4*)&a_src[s * 4];
  const float4 ad = *(const float4*)&a_dst[d * 4];
  const float asv[4] = {as.x, as.y, as.z, as.w};
  const float adv[4] = {ad.x, ad.y, ad.z, ad.w};
  float al[4];
#pragma unroll
  for (int h = 0; h < 4; ++h) {
    float ae = e0 * q[h] + e1 * q[4 + h] + e2 * q[8 + h] + e3 * q[12 + h];
    float a = asv[h] + adv[h] + ae;
    al[h] = (a >= 0.f) ? a : NEG_SLOPE * a;
  }
  float4 o = {al[0], al[1], al[2], al[3]};
  *(float4*)&alphacsr[(size_t)pos * 4] = o;
}

// ---- fused softmax + CSR gather-aggregate + BN partial stats ----
// One wave per node; lane l: channels l*8..l*8+7; head = l>>4.
// Gather unrolled x4 with group-ahead index prefetch (4 row loads in flight).
__global__ __launch_bounds__(256) void agg_fused_kernel(
    const int* __restrict__ rowstart, const int* __restrict__ csr_src,
    const float* __restrict__ alphacsr, const unsigned short* __restrict__ H16,
    float* __restrict__ out, float* __restrict__ psum, float* __restrict__ psq) {
  __shared__ float sv[4][HC];
  const int wid = threadIdx.x >> 6;
  const int n = blockIdx.x * 4 + wid;           // grid 5000 * 4 waves = 20000
  const int l = threadIdx.x & 63;
  const int head = l >> 4;
  const int j = l * 8;
  const int lo = l & 15;                        // lane within head group
  const int beg = rowstart[n], end = rowstart[n + 1];
  const float aself = alphacsr[(size_t)(N_EDGES + n) * 4 + head];
  // pass 1: per-head max (16-lane strided walk + butterfly)
  float m = aself;
  for (int p = beg + lo; p < end; p += 16)
    m = fmaxf(m, alphacsr[(size_t)p * 4 + head]);
#pragma unroll
  for (int mask = 1; mask <= 8; mask <<= 1) m = fmaxf(m, __shfl_xor(m, mask));
  // pass 2: denominator
  float den = 0.f;
  for (int p = beg + lo; p < end; p += 16)
    den += __expf(alphacsr[(size_t)p * 4 + head] - m);
#pragma unroll
  for (int mask = 1; mask <= 8; mask <<= 1) den += __shfl_xor(den, mask);
  den += __expf(aself - m);
  const float dinv = 1.0f / (den + 1e-16f);
  // pass 3: weighted gather, 4 rows in flight
  const float wself = __expf(aself - m) * dinv;
  const u16x8 hv = *(const u16x8*)&H16[(size_t)n * HC + j];
  float acc[8];
#pragma unroll
  for (int c = 0; c < 8; ++c) acc[c] = wself * bf2f(hv[c]);
  int sa = (beg     < end) ? csr_src[beg]     : n;
  int sb = (beg + 1 < end) ? csr_src[beg + 1] : n;
  int sc = (beg + 2 < end) ? csr_src[beg + 2] : n;
  int sd = (beg + 3 < end) ? csr_src[beg + 3] : n;
  for (int p = beg; p < end; p += 4) {
    const int p2 = p + 4;
    const int ta = (p2     < end) ? csr_src[p2]     : n;
    const int tb = (p2 + 1 < end) ? csr_src[p2 + 1] : n;
    const int tc = (p2 + 2 < end) ? csr_src[p2 + 2] : n;
    const int td = (p2 + 3 < end) ? csr_src[p2 + 3] : n;
    const u16x8 va = *(const u16x8*)&H16[(size_t)sa * HC + j];
    const u16x8 vb = *(const u16x8*)&H16[(size_t)sb * HC + j];
    const u16x8 vc = *(const u16x8*)&H16[(size_t)sc * HC + j];
    const u16x8 vd = *(const u16x8*)&H16[(size_t)sd * HC + j];
    const float wa = __expf(alphacsr[(size_t)p * 4 + head] - m) * dinv;
    const float wb = (p + 1 < end) ? __expf(alphacsr[(size_t)(p + 1) * 4 + head] - m) * dinv : 0.f;
    const float wc2 = (p + 2 < end) ? __expf(alphacsr[(size_t)(p + 2) * 4 + head] - m) * dinv : 0.f;
    const float wd = (p + 3 < end) ? __expf(alphacsr[(size_t)(p + 3) * 4 + head] - m) * dinv : 0.f;
#pragma unroll
    for (int c = 0; c < 8; ++c)
      acc[c] += wa * bf2f(va[c]) + wb * bf2f(vb[c]) + wc2 * bf2f(vc[c]) + wd * bf2f(vd[c]);
    sa = ta; sb = tb; sc = tc; sd = td;
  }
  float4 o0 = {acc[0], acc[1], acc[2], acc[3]};
  float4 o1 = {acc[4], acc[5], acc[6], acc[7]};
  *(float4*)&out[(size_t)n * HC + j] = o0;
  *(float4*)&out[(size_t)n * HC + j + 4] = o1;
  // ---- BN partial stats: block-level reduce then sliced atomics ----
#pragma unroll
  for (int c = 0; c < 8; ++c) sv[wid][j + c] = acc[c];
  __syncthreads();
  const int t = threadIdx.x;
  const int slice = (blockIdx.x & (NSLICE - 1)) * HC;
#pragma unroll
  for (int cc = 0; cc < 2; ++cc) {
    const int c = t + cc * 256;
    const float v0 = sv[0][c], v1 = sv[1][c], v2 = sv[2][c], v3 = sv[3][c];
    atomicAdd(&psum[slice + c], v0 + v1 + v2 + v3);
    atomicAdd(&psq[slice + c], v0 * v0 + v1 * v1 + v2 * v2 + v3 * v3);
  }
}

// ---- fold NSLICE partial stats into per-channel scale/shift (bias cancels) ----
__global__ void bn_reduce_kernel(const float* __restrict__ psum, const float* __restrict__ psq,
                                 const float* __restrict__ gamma, const float* __restrict__ beta,
                                 float* __restrict__ scale, float* __restrict__ shift) {
  const int c = threadIdx.x;     // 512
  float s = 0.f, q = 0.f;
#pragma unroll
  for (int k = 0; k < NSLICE; ++k) { s += psum[k * HC + c]; q += psq[k * HC + c]; }
  const float mu = s * (1.0f / N_NODES);
  const float var = q * (1.0f / N_NODES) - mu * mu;
  const float sc = gamma[c] * rsqrtf(var + BN_EPS);
  scale[c] = sc;
  shift[c] = beta[c] - mu * sc;
}

// ---- BN normalize with precomputed scale/shift ----
__global__ void bn_apply_kernel(float* __restrict__ out, const float* __restrict__ scale,
                                const float* __restrict__ shift) {
  const int i = blockIdx.x * blockDim.x + threadIdx.x;   // float4 index
  if (i >= N_NODES * HC / 4) return;
  const int j4 = (i & (HC / 4 - 1)) * 4;
  float4 v = ((const float4*)out)[i];
  const float4 sc = *(const float4*)&scale[j4];
  const float4 sh = *(const float4*)&shift[j4];
  v.x = v.x * sc.x + sh.x; v.y = v.y * sc.y + sh.y;
  v.z = v.z * sc.z + sh.z; v.w = v.w * sc.w + sh.w;
  ((float4*)out)[i] = v;
}

extern "C" void kernel_launch(void* const* d_in, const int* in_sizes, int n_in,
                              void* d_out, int out_size, void* d_ws, size_t ws_size,
                              hipStream_t stream) {
  const float* x     = (const float*)d_in[0];
  const int*   ei    = (const int*)d_in[1];
  const float* ea    = (const float*)d_in[2];
  const float* W     = (const float*)d_in[3];
  const float* We    = (const float*)d_in[4];
  const float* att_s = (const float*)d_in[5];
  const float* att_d = (const float*)d_in[6];
  const float* att_e = (const float*)d_in[7];
  // d_in[8] = bias: cancels exactly in BatchNorm -> unused
  const float* gamma = (const float*)d_in[9];
  const float* beta  = (const float*)d_in[10];
  float* out = (float*)d_out;
  float* ws  = (float*)d_ws;

  // workspace layout
  unsigned short* H16     = (unsigned short*)ws;                   // N*512 bf16
  float*    a_src   = (float*)(H16 + (size_t)N_NODES * HC);        // N*4
  float*    a_dst   = a_src + N_NODES * NHEAD;                     // N*4
  float*    alphacsr= a_dst + N_NODES * NHEAD;                     // TOT_E*4
  float*    qm      = alphacsr + (size_t)TOT_E * NHEAD;            // 16
  float*    scale   = qm + 16;                                     // 512
  float*    shift   = scale + HC;                                  // 512
  int*      rowstart= (int*)(shift + HC);                          // N+1 (pad 20004)
  int*      csr_src = rowstart + 20004;                            // E
  unsigned short* Ap = (unsigned short*)(csr_src + N_EDGES);       // M16_PAD*16*64*8
  unsigned short* Bp = Ap + (size_t)M16_PAD * 16 * 64 * 8;         // 32*16*64*8
  // ---- zeroed-every-call block ----
  int*      deg     = (int*)(Bp + 32 * 16 * 64 * 8);               // N
  int*      cnt     = deg + N_NODES;                               // N
  float*    msum    = (float*)(cnt + N_NODES);                     // 4
  float*    psum    = msum + 4;                                    // NSLICE*512
  float*    psq     = psum + NSLICE * HC;                          // NSLICE*512

  const size_t zero_bytes =
      (size_t)(N_NODES * 2 + 4 + NSLICE * HC * 2) * sizeof(float);
  hipMemsetAsync(deg, 0, zero_bytes, stream);

  prep_pack_kernel<<<PACK_BLOCKS + PREP_BLOCKS, 256, 0, stream>>>(
      x, W, Ap, Bp, ea, ei, We, att_e, msum, deg, qm);
  scan_kernel<<<1, 1024, 0, stream>>>(deg, rowstart);
  mfma_gemm_fused<<<dim3(157, 4), 256, 0, stream>>>(Ap, Bp, att_s, att_d, H16, a_src, a_dst);
  scatter_alpha_kernel<<<(TOT_E + 255) / 256, 256, 0, stream>>>(ei, ea, rowstart, cnt,
                                                                a_src, a_dst, msum, qm,
                                                                csr_src, alphacsr);
  agg_fused_kernel<<<N_NODES / 4, 256, 0, stream>>>(rowstart, csr_src, alphacsr, H16,
                                                    out, psum, psq);
  bn_reduce_kernel<<<1, HC, 0, stream>>>(psum, psq, gamma, beta, scale, shift);
  bn_apply_kernel<<<(N_NODES * HC / 4 + 255) / 256, 256, 0, stream>>>(out, scale, shift);
}

// Round 8
// 180.000 us; speedup vs baseline: 14.1215x; 1.0392x over previous
//
#include <hip/hip_runtime.h>
#include <math.h>

#define N_NODES 20000
#define N_EDGES 320000
#define TOT_E   340000      // E + N self loops
#define IN_F    512
#define HC      512         // H*C
#define NHEAD   4
#define CHAN    128
#define NEG_SLOPE 0.2f
#define BN_EPS  1e-5f
#define NSLICE  8           // BN partial-stat contention slices
#define AGG_BLOCKS 1250
#define NODES_PER_BLOCK 16  // 4 waves x 4 sequential nodes

#define M16_PAD 1256        // 157 row-blocks * 8 = padded count of 16-row fragments
#define PACK_BLOCKS (128 + M16_PAD * 16 * 64 / 256)   // 5152
#define PREP_BLOCKS 256

typedef short short8v __attribute__((ext_vector_type(8)));   // 8 bf16 (4 VGPRs)
typedef float f32x4  __attribute__((ext_vector_type(4)));
typedef unsigned short u16x8 __attribute__((ext_vector_type(8)));
typedef unsigned short u16x4 __attribute__((ext_vector_type(4)));

// ---- f32 -> bf16 bits, round-to-nearest-even ----
__device__ __forceinline__ unsigned short f2bf(float f) {
  unsigned u = __float_as_uint(f);
  return (unsigned short)((u + 0x7FFFu + ((u >> 16) & 1u)) >> 16);
}
__device__ __forceinline__ float bf2f(unsigned short b) {
  return __uint_as_float(((unsigned)b) << 16);
}

// ---- fused: pack A/B fragments (blocks 0..PACK_BLOCKS) + prep (histogram,
//      edge-attr colsums, qmat) on the trailing PREP_BLOCKS blocks ----
__global__ void prep_pack_kernel(const float* __restrict__ X, const float* __restrict__ W,
                                 unsigned short* __restrict__ Ap, unsigned short* __restrict__ Bp,
                                 const float* __restrict__ EA, const int* __restrict__ EI,
                                 const float* __restrict__ We, const float* __restrict__ aedg,
                                 float* __restrict__ msum, int* __restrict__ deg,
                                 float* __restrict__ qm) {
  if (blockIdx.x < 128) {
    // pack B: Bp[((n16*16 + k32)*64 + l)*8 + j] = W[k32*32+(l>>4)*8+j][n16*16+(l&15)]
    const int tid = blockIdx.x * blockDim.x + threadIdx.x;   // 32768
    const int l = tid & 63;
    const int k32 = (tid >> 6) & 15;
    const int n16 = tid >> 10;
    const int col = n16 * 16 + (l & 15);
    const int k = k32 * 32 + ((l >> 4) << 3);
    unsigned short v[8];
#pragma unroll
    for (int j = 0; j < 8; ++j) v[j] = f2bf(W[(size_t)(k + j) * HC + col]);
    *(short8v*)&Bp[(size_t)tid * 8] = *(short8v*)v;
  } else if (blockIdx.x < PACK_BLOCKS) {
    // pack A: Ap[((m16*16 + k32)*64 + l)*8 + j] = x[m16*16+(l&15)][k32*32+(l>>4)*8+j]
    const int tid = (blockIdx.x - 128) * blockDim.x + threadIdx.x; // M16_PAD*16*64
    const int l = tid & 63;
    const int k32 = (tid >> 6) & 15;
    const int m16 = tid >> 10;
    const int row = m16 * 16 + (l & 15);
    const int k = k32 * 32 + ((l >> 4) << 3);
    unsigned short v[8] = {0, 0, 0, 0, 0, 0, 0, 0};
    if (row < N_NODES) {
      const float4 f0 = *(const float4*)&X[(size_t)row * IN_F + k];
      const float4 f1 = *(const float4*)&X[(size_t)row * IN_F + k + 4];
      v[0] = f2bf(f0.x); v[1] = f2bf(f0.y); v[2] = f2bf(f0.z); v[3] = f2bf(f0.w);
      v[4] = f2bf(f1.x); v[5] = f2bf(f1.y); v[6] = f2bf(f1.z); v[7] = f2bf(f1.w);
    }
    *(short8v*)&Ap[(size_t)tid * 8] = *(short8v*)v;
  } else {
    const int bid = blockIdx.x - PACK_BLOCKS;    // 0..255
    // qmat: q[d][h] = sum_c W_edge[d, h*C+c] * att_edge[h, c]
    if (bid < 16 && threadIdx.x < 64) {
      const int d = bid >> 2, h = bid & 3, lane = threadIdx.x;
      const int base = h * CHAN + lane * 2;
      float v = We[d * HC + base] * aedg[base] + We[d * HC + base + 1] * aedg[base + 1];
#pragma unroll
      for (int m = 32; m >= 1; m >>= 1) v += __shfl_down(v, m);
      if (lane == 0) qm[d * 4 + h] = v;
    }
    float s0 = 0.f, s1 = 0.f, s2 = 0.f, s3 = 0.f;
    for (int i = bid * blockDim.x + threadIdx.x; i < N_EDGES;
         i += PREP_BLOCKS * blockDim.x) {
      const float4 v = *(const float4*)&EA[(size_t)i * 4];
      s0 += v.x; s1 += v.y; s2 += v.z; s3 += v.w;
      atomicAdd(&deg[EI[N_EDGES + i]], 1);
    }
#pragma unroll
    for (int m = 32; m >= 1; m >>= 1) {
      s0 += __shfl_down(s0, m); s1 += __shfl_down(s1, m);
      s2 += __shfl_down(s2, m); s3 += __shfl_down(s3, m);
    }
    __shared__ float red[4][4];
    const int lane = threadIdx.x & 63, wid = threadIdx.x >> 6;
    if (lane == 0) { red[wid][0] = s0; red[wid][1] = s1; red[wid][2] = s2; red[wid][3] = s3; }
    __syncthreads();
    if (threadIdx.x < 4) {
      float v = red[0][threadIdx.x] + red[1][threadIdx.x] + red[2][threadIdx.x] + red[3][threadIdx.x];
      atomicAdd(&msum[threadIdx.x], v);
    }
  }
}

// ---- exclusive prefix sum over deg[20000] -> rowstart[20001]; one block/1024thr ----
__global__ __launch_bounds__(1024) void scan_kernel(const int* __restrict__ deg,
                                                    int* __restrict__ rowstart) {
  __shared__ int part[1024];
  const int t = threadIdx.x;
  const int base = t * 20;
  int local[20];
  int s = 0;
#pragma unroll
  for (int i = 0; i < 20; ++i) {
    const int idx = base + i;
    const int v = (idx < N_NODES) ? deg[idx] : 0;
    local[i] = s;           // exclusive within chunk
    s += v;
  }
  part[t] = s;
  __syncthreads();
  for (int off = 1; off < 1024; off <<= 1) {
    const int v = (t >= off) ? part[t - off] : 0;
    __syncthreads();
    part[t] += v;
    __syncthreads();
  }
  const int excl = (t > 0) ? part[t - 1] : 0;
#pragma unroll
  for (int i = 0; i < 20; ++i) {
    const int idx = base + i;
    if (idx < N_NODES) rowstart[idx] = excl + local[i];
  }
  if (t == 1023) rowstart[N_NODES] = part[1023];
}

// ---- h = x @ W via bf16 MFMA; writes h as bf16; fuses per-head att dots ----
// blockIdx.y == head (128 cols). a_src/a_dst computed exactly (f32 acc).
__global__ __launch_bounds__(256) void mfma_gemm_fused(const unsigned short* __restrict__ Ap_,
                                                       const unsigned short* __restrict__ Bp_,
                                                       const float* __restrict__ att_s,
                                                       const float* __restrict__ att_d,
                                                       unsigned short* __restrict__ H16,
                                                       float* __restrict__ a_src,
                                                       float* __restrict__ a_dst) {
  const short8v* __restrict__ Ap = (const short8v*)Ap_;
  const short8v* __restrict__ Bp = (const short8v*)Bp_;
  const int tid = threadIdx.x;
  const int l = tid & 63;
  const int w = tid >> 6;                 // 4 waves, 2x2
  const int wr = w >> 1, wc = w & 1;
  const int bm16 = blockIdx.x * 8 + wr * 4;   // 16-row fragment base (global)
  const int bn16 = blockIdx.y * 8 + wc * 4;   // 16-col fragment base
  const int head = blockIdx.y;
  f32x4 acc[4][4] = {};
#pragma unroll 2
  for (int kk = 0; kk < IN_F / 32; ++kk) {
    short8v a[4], b[4];
#pragma unroll
    for (int m = 0; m < 4; ++m) a[m] = Ap[((size_t)(bm16 + m) * 16 + kk) * 64 + l];
#pragma unroll
    for (int n = 0; n < 4; ++n) b[n] = Bp[((size_t)(bn16 + n) * 16 + kk) * 64 + l];
#pragma unroll
    for (int m = 0; m < 4; ++m)
#pragma unroll
      for (int n = 0; n < 4; ++n)
        acc[m][n] = __builtin_amdgcn_mfma_f32_16x16x32_bf16(a[m], b[n], acc[m][n], 0, 0, 0);
  }
  const int rbase = (l >> 4) * 4;   // C/D: col = l&15, row = (l>>4)*4 + r
  const int cl = l & 15;
  // ---- store h in bf16 ----
#pragma unroll
  for (int m = 0; m < 4; ++m) {
#pragma unroll
    for (int r = 0; r < 4; ++r) {
      const int row = (bm16 + m) * 16 + rbase + r;
      if (row < N_NODES) {
#pragma unroll
        for (int n = 0; n < 4; ++n)
          H16[(size_t)row * HC + (bn16 + n) * 16 + cl] = f2bf(acc[m][n][r]);
      }
    }
  }
  // ---- fused att dots: this block covers exactly head `blockIdx.y` ----
  float as_v[4], ad_v[4];
#pragma unroll
  for (int n = 0; n < 4; ++n) {
    const int c = head * CHAN + wc * 64 + n * 16 + cl;
    as_v[n] = att_s[c];
    ad_v[n] = att_d[c];
  }
  __shared__ float red[2][2][2][64];   // [s/d][wc][wr][row_local]
#pragma unroll
  for (int m = 0; m < 4; ++m) {
#pragma unroll
    for (int r = 0; r < 4; ++r) {
      float ps = 0.f, pd = 0.f;
#pragma unroll
      for (int n = 0; n < 4; ++n) { ps += acc[m][n][r] * as_v[n]; pd += acc[m][n][r] * ad_v[n]; }
#pragma unroll
      for (int mask = 1; mask <= 8; mask <<= 1) {
        ps += __shfl_xor(ps, mask); pd += __shfl_xor(pd, mask);
      }
      if (cl == 0) {
        const int rl = m * 16 + rbase + r;
        red[0][wc][wr][rl] = ps;
        red[1][wc][wr][rl] = pd;
      }
    }
  }
  __syncthreads();
  if (tid < 128) {
    const int row = blockIdx.x * 128 + tid;
    if (row < N_NODES) {
      const int wr2 = tid >> 6, rl = tid & 63;
      a_src[row * 4 + head] = red[0][0][wr2][rl] + red[0][1][wr2][rl];
      a_dst[row * 4 + head] = red[1][0][wr2][rl] + red[1][1][wr2][rl];
    }
  }
}

// ---- fused scatter + alpha: CSR position + leaky-relu'd alpha written in CSR order ----
__global__ void scatter_alpha_kernel(const int* __restrict__ EI, const float* __restrict__ EA,
                                     const int* __restrict__ rowstart, int* __restrict__ cnt,
                                     const float* __restrict__ a_src, const float* __restrict__ a_dst,
                                     const float* __restrict__ msum, const float* __restrict__ q,
                                     int* __restrict__ csr_src, float* __restrict__ alphacsr) {
  const int k = blockIdx.x * blockDim.x + threadIdx.x;
  if (k >= TOT_E) return;
  int s, d, pos;
  float e0, e1, e2, e3;
  if (k < N_EDGES) {
    s = EI[k]; d = EI[N_EDGES + k];
    const float4 e = *(const float4*)&EA[(size_t)k * 4];
    e0 = e.x; e1 = e.y; e2 = e.z; e3 = e.w;
    pos = rowstart[d] + atomicAdd(&cnt[d], 1);
    csr_src[pos] = s;
  } else {
    s = d = k - N_EDGES;
    const float inv = 1.0f / (float)N_EDGES;
    e0 = msum[0] * inv; e1 = msum[1] * inv; e2 = msum[2] * inv; e3 = msum[3] * inv;
    pos = k;                       // self region: identity
  }
  const float4 as = *(const float4*)&a_src[s * 4];
  const float4 ad = *(const float4*)&a_dst[d * 4];
  const float asv[4] = {as.x, as.y, as.z, as.w};
  const float adv[4] = {ad.x, ad.y, ad.z, ad.w};
  float al[4];
#pragma unroll
  for (int h = 0; h < 4; ++h) {
    float ae = e0 * q[h] + e1 * q[4 + h] + e2 * q[8 + h] + e3 * q[12 + h];
    float a = asv[h] + adv[h] + ae;
    al[h] = (a >= 0.f) ? a : NEG_SLOPE * a;
  }
  float4 o = {al[0], al[1], al[2], al[3]};
  *(float4*)&alphacsr[(size_t)pos * 4] = o;
}

// ---- fused softmax + CSR gather-aggregate (bf16 out) + BN partial stats ----
// One wave per node, 4 sequential nodes per wave; lane l: channels l*8..l*8+7.
// Per-wave register accumulation of BN sum/sq; one LDS reduce + 1024 atomics/block.
__global__ __launch_bounds__(256) void agg_fused_kernel(
    const int* __restrict__ rowstart, const int* __restrict__ csr_src,
    const float* __restrict__ alphacsr, const unsigned short* __restrict__ H16,
    unsigned short* __restrict__ o16, float* __restrict__ psum, float* __restrict__ psq) {
  __shared__ float sv[4][HC];
  const int wid = threadIdx.x >> 6;
  const int l = threadIdx.x & 63;
  const int head = l >> 4;
  const int j = l * 8;
  const int lo = l & 15;                        // lane within head group
  float ssum[8] = {0.f, 0.f, 0.f, 0.f, 0.f, 0.f, 0.f, 0.f};
  float ssq[8]  = {0.f, 0.f, 0.f, 0.f, 0.f, 0.f, 0.f, 0.f};
#pragma unroll 1
  for (int g = 0; g < NODES_PER_BLOCK / 4; ++g) {
    const int n = blockIdx.x * NODES_PER_BLOCK + g * 4 + wid;   // < 20000 exact
    const int beg = rowstart[n], end = rowstart[n + 1];
    const float aself = alphacsr[(size_t)(N_EDGES + n) * 4 + head];
    // pass 1: per-head max (16-lane strided walk + butterfly)
    float m = aself;
    for (int p = beg + lo; p < end; p += 16)
      m = fmaxf(m, alphacsr[(size_t)p * 4 + head]);
#pragma unroll
    for (int mask = 1; mask <= 8; mask <<= 1) m = fmaxf(m, __shfl_xor(m, mask));
    // pass 2: denominator
    float den = 0.f;
    for (int p = beg + lo; p < end; p += 16)
      den += __expf(alphacsr[(size_t)p * 4 + head] - m);
#pragma unroll
    for (int mask = 1; mask <= 8; mask <<= 1) den += __shfl_xor(den, mask);
    den += __expf(aself - m);
    const float dinv = 1.0f / (den + 1e-16f);
    // pass 3: weighted gather, 1-ahead index prefetch
    const float wself = __expf(aself - m) * dinv;
    const u16x8 hv = *(const u16x8*)&H16[(size_t)n * HC + j];
    float acc[8];
#pragma unroll
    for (int c = 0; c < 8; ++c) acc[c] = wself * bf2f(hv[c]);
    int s_nxt = 0;
    if (beg < end) s_nxt = csr_src[beg];
    for (int idx = beg; idx < end; ++idx) {
      const int s = s_nxt;
      if (idx + 1 < end) s_nxt = csr_src[idx + 1];
      const float w = __expf(alphacsr[(size_t)idx * 4 + head] - m) * dinv;
      const u16x8 v = *(const u16x8*)&H16[(size_t)s * HC + j];
#pragma unroll
      for (int c = 0; c < 8; ++c) acc[c] += w * bf2f(v[c]);
    }
    unsigned short ov[8];
#pragma unroll
    for (int c = 0; c < 8; ++c) {
      ov[c] = f2bf(acc[c]);
      ssum[c] += acc[c];
      ssq[c] += acc[c] * acc[c];
    }
    *(short8v*)&o16[(size_t)n * HC + j] = *(short8v*)ov;
  }
  // ---- block-level BN stat reduce (2 rounds over one 8KB LDS buffer) ----
  const int t = threadIdx.x;
  const int slice = (blockIdx.x & (NSLICE - 1)) * HC;
#pragma unroll
  for (int c = 0; c < 8; ++c) sv[wid][j + c] = ssum[c];
  __syncthreads();
  const float r0 = sv[0][t] + sv[1][t] + sv[2][t] + sv[3][t];
  const float r1 = sv[0][t + 256] + sv[1][t + 256] + sv[2][t + 256] + sv[3][t + 256];
  __syncthreads();
#pragma unroll
  for (int c = 0; c < 8; ++c) sv[wid][j + c] = ssq[c];
  __syncthreads();
  const float q0 = sv[0][t] + sv[1][t] + sv[2][t] + sv[3][t];
  const float q1 = sv[0][t + 256] + sv[1][t + 256] + sv[2][t + 256] + sv[3][t + 256];
  atomicAdd(&psum[slice + t], r0);
  atomicAdd(&psum[slice + t + 256], r1);
  atomicAdd(&psq[slice + t], q0);
  atomicAdd(&psq[slice + t + 256], q1);
}

// ---- fold NSLICE partial stats into per-channel scale/shift (bias cancels) ----
__global__ void bn_reduce_kernel(const float* __restrict__ psum, const float* __restrict__ psq,
                                 const float* __restrict__ gamma, const float* __restrict__ beta,
                                 float* __restrict__ scale, float* __restrict__ shift) {
  const int c = threadIdx.x;     // 512
  float s = 0.f, q = 0.f;
#pragma unroll
  for (int k = 0; k < NSLICE; ++k) { s += psum[k * HC + c]; q += psq[k * HC + c]; }
  const float mu = s * (1.0f / N_NODES);
  const float var = q * (1.0f / N_NODES) - mu * mu;
  const float sc = gamma[c] * rsqrtf(var + BN_EPS);
  scale[c] = sc;
  shift[c] = beta[c] - mu * sc;
}

// ---- BN normalize: read bf16 pre-BN rows, write final f32 out ----
__global__ void bn_apply_kernel(const unsigned short* __restrict__ o16,
                                const float* __restrict__ scale,
                                const float* __restrict__ shift,
                                float* __restrict__ out) {
  const int i = blockIdx.x * blockDim.x + threadIdx.x;   // float4 index
  if (i >= N_NODES * HC / 4) return;
  const int j4 = (i & (HC / 4 - 1)) * 4;
  const u16x4 v16 = *(const u16x4*)&o16[(size_t)i * 4];
  const float4 sc = *(const float4*)&scale[j4];
  const float4 sh = *(const float4*)&shift[j4];
  float4 v;
  v.x = bf2f(v16[0]) * sc.x + sh.x;
  v.y = bf2f(v16[1]) * sc.y + sh.y;
  v.z = bf2f(v16[2]) * sc.z + sh.z;
  v.w = bf2f(v16[3]) * sc.w + sh.w;
  ((float4*)out)[i] = v;
}

extern "C" void kernel_launch(void* const* d_in, const int* in_sizes, int n_in,
                              void* d_out, int out_size, void* d_ws, size_t ws_size,
                              hipStream_t stream) {
  const float* x     = (const float*)d_in[0];
  const int*   ei    = (const int*)d_in[1];
  const float* ea    = (const float*)d_in[2];
  const float* W     = (const float*)d_in[3];
  const float* We    = (const float*)d_in[4];
  const float* att_s = (const float*)d_in[5];
  const float* att_d = (const float*)d_in[6];
  const float* att_e = (const float*)d_in[7];
  // d_in[8] = bias: cancels exactly in BatchNorm -> unused
  const float* gamma = (const float*)d_in[9];
  const float* beta  = (const float*)d_in[10];
  float* out = (float*)d_out;
  float* ws  = (float*)d_ws;

  // workspace layout
  unsigned short* H16     = (unsigned short*)ws;                   // N*512 bf16
  float*    a_src   = (float*)(H16 + (size_t)N_NODES * HC);        // N*4
  float*    a_dst   = a_src + N_NODES * NHEAD;                     // N*4
  float*    alphacsr= a_dst + N_NODES * NHEAD;                     // TOT_E*4
  float*    qm      = alphacsr + (size_t)TOT_E * NHEAD;            // 16
  float*    scale   = qm + 16;                                     // 512
  float*    shift   = scale + HC;                                  // 512
  int*      rowstart= (int*)(shift + HC);                          // N+1 (pad 20004)
  int*      csr_src = rowstart + 20004;                            // E
  unsigned short* Ap = (unsigned short*)(csr_src + N_EDGES);       // M16_PAD*16*64*8
  unsigned short* Bp = Ap + (size_t)M16_PAD * 16 * 64 * 8;         // 32*16*64*8
  unsigned short* o16 = Ap;   // Ap is dead after the GEMM; reuse as bf16 pre-BN out
  // ---- zeroed-every-call block ----
  int*      deg     = (int*)(Bp + 32 * 16 * 64 * 8);               // N
  int*      cnt     = deg + N_NODES;                               // N
  float*    msum    = (float*)(cnt + N_NODES);                     // 4
  float*    psum    = msum + 4;                                    // NSLICE*512
  float*    psq     = psum + NSLICE * HC;                          // NSLICE*512

  const size_t zero_bytes =
      (size_t)(N_NODES * 2 + 4 + NSLICE * HC * 2) * sizeof(float);
  hipMemsetAsync(deg, 0, zero_bytes, stream);

  prep_pack_kernel<<<PACK_BLOCKS + PREP_BLOCKS, 256, 0, stream>>>(
      x, W, Ap, Bp, ea, ei, We, att_e, msum, deg, qm);
  scan_kernel<<<1, 1024, 0, stream>>>(deg, rowstart);
  mfma_gemm_fused<<<dim3(157, 4), 256, 0, stream>>>(Ap, Bp, att_s, att_d, H16, a_src, a_dst);
  scatter_alpha_kernel<<<(TOT_E + 255) / 256, 256, 0, stream>>>(ei, ea, rowstart, cnt,
                                                                a_src, a_dst, msum, qm,
                                                                csr_src, alphacsr);
  agg_fused_kernel<<<AGG_BLOCKS, 256, 0, stream>>>(rowstart, csr_src, alphacsr, H16,
                                                   o16, psum, psq);
  bn_reduce_kernel<<<1, HC, 0, stream>>>(psum, psq, gamma, beta, scale, shift);
  bn_apply_kernel<<<(N_NODES * HC / 4 + 255) / 256, 256, 0, stream>>>(o16, scale, shift, out);
}

// Round 9
// 174.280 us; speedup vs baseline: 14.5850x; 1.0328x over previous
//
#include <hip/hip_runtime.h>
#include <math.h>

#define N_NODES 20000
#define N_EDGES 320000
#define TOT_E   340000      // E + N self loops
#define IN_F    512
#define HC      512         // H*C
#define NHEAD   4
#define CHAN    128
#define NEG_SLOPE 0.2f
#define BN_EPS  1e-5f
#define NSLICE  8           // BN partial-stat contention slices
#define AGG_BLOCKS 2500
#define NODES_PER_BLOCK 8   // 4 waves x 2 sequential nodes

#define GEMM_BM 32
#define LDS_STRIDE 72       // bf16 elems per LDS row: 64 + 8 pad (144B)

#define PACK_BLOCKS 128     // B-pack blocks
#define PREP_BLOCKS 256

typedef short short8v __attribute__((ext_vector_type(8)));   // 8 bf16 (4 VGPRs)
typedef float f32x4  __attribute__((ext_vector_type(4)));
typedef unsigned short u16x8 __attribute__((ext_vector_type(8)));
typedef unsigned short u16x4 __attribute__((ext_vector_type(4)));

// ---- f32 -> bf16 bits, round-to-nearest-even ----
__device__ __forceinline__ unsigned short f2bf(float f) {
  unsigned u = __float_as_uint(f);
  return (unsigned short)((u + 0x7FFFu + ((u >> 16) & 1u)) >> 16);
}
__device__ __forceinline__ float bf2f(unsigned short b) {
  return __uint_as_float(((unsigned)b) << 16);
}

// ---- fused: pack B fragments (blocks 0..127) + prep (histogram, edge-attr
//      colsums, qmat) on the trailing PREP_BLOCKS blocks ----
__global__ void prep_pack_kernel(const float* __restrict__ W,
                                 unsigned short* __restrict__ Bp,
                                 const float* __restrict__ EA, const int* __restrict__ EI,
                                 const float* __restrict__ We, const float* __restrict__ aedg,
                                 float* __restrict__ msum, int* __restrict__ deg,
                                 float* __restrict__ qm) {
  if (blockIdx.x < PACK_BLOCKS) {
    // pack B: Bp[((n16*16 + k32)*64 + l)*8 + j] = W[k32*32+(l>>4)*8+j][n16*16+(l&15)]
    const int tid = blockIdx.x * blockDim.x + threadIdx.x;   // 32768
    const int l = tid & 63;
    const int k32 = (tid >> 6) & 15;
    const int n16 = tid >> 10;
    const int col = n16 * 16 + (l & 15);
    const int k = k32 * 32 + ((l >> 4) << 3);
    unsigned short v[8];
#pragma unroll
    for (int j = 0; j < 8; ++j) v[j] = f2bf(W[(size_t)(k + j) * HC + col]);
    *(short8v*)&Bp[(size_t)tid * 8] = *(short8v*)v;
  } else {
    const int bid = blockIdx.x - PACK_BLOCKS;    // 0..255
    // qmat: q[d][h] = sum_c W_edge[d, h*C+c] * att_edge[h, c]
    if (bid < 16 && threadIdx.x < 64) {
      const int d = bid >> 2, h = bid & 3, lane = threadIdx.x;
      const int base = h * CHAN + lane * 2;
      float v = We[d * HC + base] * aedg[base] + We[d * HC + base + 1] * aedg[base + 1];
#pragma unroll
      for (int m = 32; m >= 1; m >>= 1) v += __shfl_down(v, m);
      if (lane == 0) qm[d * 4 + h] = v;
    }
    float s0 = 0.f, s1 = 0.f, s2 = 0.f, s3 = 0.f;
    for (int i = bid * blockDim.x + threadIdx.x; i < N_EDGES;
         i += PREP_BLOCKS * blockDim.x) {
      const float4 v = *(const float4*)&EA[(size_t)i * 4];
      s0 += v.x; s1 += v.y; s2 += v.z; s3 += v.w;
      atomicAdd(&deg[EI[N_EDGES + i]], 1);
    }
#pragma unroll
    for (int m = 32; m >= 1; m >>= 1) {
      s0 += __shfl_down(s0, m); s1 += __shfl_down(s1, m);
      s2 += __shfl_down(s2, m); s3 += __shfl_down(s3, m);
    }
    __shared__ float red[4][4];
    const int lane = threadIdx.x & 63, wid = threadIdx.x >> 6;
    if (lane == 0) { red[wid][0] = s0; red[wid][1] = s1; red[wid][2] = s2; red[wid][3] = s3; }
    __syncthreads();
    if (threadIdx.x < 4) {
      float v = red[0][threadIdx.x] + red[1][threadIdx.x] + red[2][threadIdx.x] + red[3][threadIdx.x];
      atomicAdd(&msum[threadIdx.x], v);
    }
  }
}

// ---- exclusive prefix sum over deg[20000] -> rowstart[20001]; one block/1024thr ----
__global__ __launch_bounds__(1024) void scan_kernel(const int* __restrict__ deg,
                                                    int* __restrict__ rowstart) {
  __shared__ int part[1024];
  const int t = threadIdx.x;
  const int base = t * 20;
  int local[20];
  int s = 0;
#pragma unroll
  for (int i = 0; i < 20; ++i) {
    const int idx = base + i;
    const int v = (idx < N_NODES) ? deg[idx] : 0;
    local[i] = s;           // exclusive within chunk
    s += v;
  }
  part[t] = s;
  __syncthreads();
  for (int off = 1; off < 1024; off <<= 1) {
    const int v = (t >= off) ? part[t - off] : 0;
    __syncthreads();
    part[t] += v;
    __syncthreads();
  }
  const int excl = (t > 0) ? part[t - 1] : 0;
#pragma unroll
  for (int i = 0; i < 20; ++i) {
    const int idx = base + i;
    if (idx < N_NODES) rowstart[idx] = excl + local[i];
  }
  if (t == 1023) rowstart[N_NODES] = part[1023];
}

// ---- h = x @ W via bf16 MFMA, x read DIRECTLY (f32->bf16 LDS staging) ----
// BM=32 rows/block, full 512 cols; wave w == head w (cols w*128..+128).
// Fused per-head att dots (pure shfl reduce, no LDS).
__global__ __launch_bounds__(256) void gemm_direct_fused(
    const float* __restrict__ X, const unsigned short* __restrict__ Bp_,
    const float* __restrict__ att_s, const float* __restrict__ att_d,
    unsigned short* __restrict__ H16, float* __restrict__ a_src,
    float* __restrict__ a_dst) {
  __shared__ unsigned short As[GEMM_BM * LDS_STRIDE];   // 4608 B
  const short8v* __restrict__ Bp = (const short8v*)Bp_;
  const int tid = threadIdx.x;
  const int l = tid & 63;
  const int w = tid >> 6;                  // wave index == head == col quarter
  const int bm = blockIdx.x * GEMM_BM;     // 625 blocks * 32 = 20000 exact
  // staging: thread t loads 8 f32 of row (t>>3), k-chunk (t&7)*8
  const int srow = tid >> 3;
  const int skc = (tid & 7) * 8;
  const int grow = bm + srow;
  // fragment read indices
  const int fr = l & 15;                   // row-in-frag
  const int fg = l >> 4;                   // 8-elem k-chunk 0..3
  const int cl = l & 15;
  f32x4 acc[2][8] = {};
  for (int k0 = 0; k0 < IN_F; k0 += 64) {
    float4 f0 = {0.f, 0.f, 0.f, 0.f}, f1 = {0.f, 0.f, 0.f, 0.f};
    if (grow < N_NODES) {
      f0 = *(const float4*)&X[(size_t)grow * IN_F + k0 + skc];
      f1 = *(const float4*)&X[(size_t)grow * IN_F + k0 + skc + 4];
    }
    unsigned short vv[8] = {f2bf(f0.x), f2bf(f0.y), f2bf(f0.z), f2bf(f0.w),
                            f2bf(f1.x), f2bf(f1.y), f2bf(f1.z), f2bf(f1.w)};
    __syncthreads();                        // previous-iter reads done
    *(short8v*)&As[srow * LDS_STRIDE + skc] = *(short8v*)vv;
    __syncthreads();
#pragma unroll
    for (int ks = 0; ks < 2; ++ks) {
      const int kk = (k0 >> 5) + ks;        // global 32-k index for B
      short8v a[2], b[8];
#pragma unroll
      for (int m = 0; m < 2; ++m)
        a[m] = *(const short8v*)&As[(m * 16 + fr) * LDS_STRIDE + ks * 32 + fg * 8];
#pragma unroll
      for (int n = 0; n < 8; ++n)
        b[n] = Bp[((size_t)(w * 8 + n) * 16 + kk) * 64 + l];
#pragma unroll
      for (int m = 0; m < 2; ++m)
#pragma unroll
        for (int n = 0; n < 8; ++n)
          acc[m][n] = __builtin_amdgcn_mfma_f32_16x16x32_bf16(a[m], b[n], acc[m][n], 0, 0, 0);
    }
  }
  // ---- store h in bf16 (C/D: col = l&15, row = (l>>4)*4 + r) ----
  const int rbase = fg * 4;
#pragma unroll
  for (int m = 0; m < 2; ++m) {
#pragma unroll
    for (int r = 0; r < 4; ++r) {
      const int row = bm + m * 16 + rbase + r;
#pragma unroll
      for (int n = 0; n < 8; ++n)
        H16[(size_t)row * HC + (w * 8 + n) * 16 + cl] = f2bf(acc[m][n][r]);
    }
  }
  // ---- fused att dots: wave w holds ALL 128 cols of head w ----
  float as_v[8], ad_v[8];
#pragma unroll
  for (int n = 0; n < 8; ++n) {
    const int c = w * CHAN + n * 16 + cl;
    as_v[n] = att_s[c];
    ad_v[n] = att_d[c];
  }
#pragma unroll
  for (int m = 0; m < 2; ++m) {
#pragma unroll
    for (int r = 0; r < 4; ++r) {
      float ps = 0.f, pd = 0.f;
#pragma unroll
      for (int n = 0; n < 8; ++n) { ps += acc[m][n][r] * as_v[n]; pd += acc[m][n][r] * ad_v[n]; }
#pragma unroll
      for (int mask = 1; mask <= 8; mask <<= 1) {
        ps += __shfl_xor(ps, mask); pd += __shfl_xor(pd, mask);
      }
      if (cl == 0) {
        const int row = bm + m * 16 + rbase + r;
        a_src[row * 4 + w] = ps;
        a_dst[row * 4 + w] = pd;
      }
    }
  }
}

// ---- fused scatter + alpha: CSR position + leaky-relu'd alpha written in CSR order ----
__global__ void scatter_alpha_kernel(const int* __restrict__ EI, const float* __restrict__ EA,
                                     const int* __restrict__ rowstart, int* __restrict__ cnt,
                                     const float* __restrict__ a_src, const float* __restrict__ a_dst,
                                     const float* __restrict__ msum, const float* __restrict__ q,
                                     int* __restrict__ csr_src, float* __restrict__ alphacsr) {
  const int k = blockIdx.x * blockDim.x + threadIdx.x;
  if (k >= TOT_E) return;
  int s, d, pos;
  float e0, e1, e2, e3;
  if (k < N_EDGES) {
    s = EI[k]; d = EI[N_EDGES + k];
    const float4 e = *(const float4*)&EA[(size_t)k * 4];
    e0 = e.x; e1 = e.y; e2 = e.z; e3 = e.w;
    pos = rowstart[d] + atomicAdd(&cnt[d], 1);
    csr_src[pos] = s;
  } else {
    s = d = k - N_EDGES;
    const float inv = 1.0f / (float)N_EDGES;
    e0 = msum[0] * inv; e1 = msum[1] * inv; e2 = msum[2] * inv; e3 = msum[3] * inv;
    pos = k;                       // self region: identity
  }
  const float4 as = *(const float4*)&a_src[s * 4];
  const float4 ad = *(const float4*)&a_dst[d * 4];
  const float asv[4] = {as.x, as.y, as.z, as.w};
  const float adv[4] = {ad.x, ad.y, ad.z, ad.w};
  float al[4];
#pragma unroll
  for (int h = 0; h < 4; ++h) {
    float ae = e0 * q[h] + e1 * q[4 + h] + e2 * q[8 + h] + e3 * q[12 + h];
    float a = asv[h] + adv[h] + ae;
    al[h] = (a >= 0.f) ? a : NEG_SLOPE * a;
  }
  float4 o = {al[0], al[1], al[2], al[3]};
  *(float4*)&alphacsr[(size_t)pos * 4] = o;
}

// ---- fused softmax + CSR gather-aggregate (bf16 out) + BN partial stats ----
// One wave per node, 2 sequential nodes per wave; lane l: channels l*8..l*8+7.
__global__ __launch_bounds__(256) void agg_fused_kernel(
    const int* __restrict__ rowstart, const int* __restrict__ csr_src,
    const float* __restrict__ alphacsr, const unsigned short* __restrict__ H16,
    unsigned short* __restrict__ o16, float* __restrict__ psum, float* __restrict__ psq) {
  __shared__ float sv[4][HC];
  const int wid = threadIdx.x >> 6;
  const int l = threadIdx.x & 63;
  const int head = l >> 4;
  const int j = l * 8;
  const int lo = l & 15;                        // lane within head group
  float ssum[8] = {0.f, 0.f, 0.f, 0.f, 0.f, 0.f, 0.f, 0.f};
  float ssq[8]  = {0.f, 0.f, 0.f, 0.f, 0.f, 0.f, 0.f, 0.f};
#pragma unroll 1
  for (int g = 0; g < NODES_PER_BLOCK / 4; ++g) {
    const int n = blockIdx.x * NODES_PER_BLOCK + g * 4 + wid;   // < 20000 exact
    const int beg = rowstart[n], end = rowstart[n + 1];
    const float aself = alphacsr[(size_t)(N_EDGES + n) * 4 + head];
    // pass 1: per-head max (16-lane strided walk + butterfly)
    float m = aself;
    for (int p = beg + lo; p < end; p += 16)
      m = fmaxf(m, alphacsr[(size_t)p * 4 + head]);
#pragma unroll
    for (int mask = 1; mask <= 8; mask <<= 1) m = fmaxf(m, __shfl_xor(m, mask));
    // pass 2: denominator
    float den = 0.f;
    for (int p = beg + lo; p < end; p += 16)
      den += __expf(alphacsr[(size_t)p * 4 + head] - m);
#pragma unroll
    for (int mask = 1; mask <= 8; mask <<= 1) den += __shfl_xor(den, mask);
    den += __expf(aself - m);
    const float dinv = 1.0f / (den + 1e-16f);
    // pass 3: weighted gather, 1-ahead index prefetch
    const float wself = __expf(aself - m) * dinv;
    const u16x8 hv = *(const u16x8*)&H16[(size_t)n * HC + j];
    float acc[8];
#pragma unroll
    for (int c = 0; c < 8; ++c) acc[c] = wself * bf2f(hv[c]);
    int s_nxt = 0;
    if (beg < end) s_nxt = csr_src[beg];
    for (int idx = beg; idx < end; ++idx) {
      const int s = s_nxt;
      if (idx + 1 < end) s_nxt = csr_src[idx + 1];
      const float w = __expf(alphacsr[(size_t)idx * 4 + head] - m) * dinv;
      const u16x8 v = *(const u16x8*)&H16[(size_t)s * HC + j];
#pragma unroll
      for (int c = 0; c < 8; ++c) acc[c] += w * bf2f(v[c]);
    }
    unsigned short ov[8];
#pragma unroll
    for (int c = 0; c < 8; ++c) {
      ov[c] = f2bf(acc[c]);
      ssum[c] += acc[c];
      ssq[c] += acc[c] * acc[c];
    }
    *(short8v*)&o16[(size_t)n * HC + j] = *(short8v*)ov;
  }
  // ---- block-level BN stat reduce (2 rounds over one 8KB LDS buffer) ----
  const int t = threadIdx.x;
  const int slice = (blockIdx.x & (NSLICE - 1)) * HC;
#pragma unroll
  for (int c = 0; c < 8; ++c) sv[wid][j + c] = ssum[c];
  __syncthreads();
  const float r0 = sv[0][t] + sv[1][t] + sv[2][t] + sv[3][t];
  const float r1 = sv[0][t + 256] + sv[1][t + 256] + sv[2][t + 256] + sv[3][t + 256];
  __syncthreads();
#pragma unroll
  for (int c = 0; c < 8; ++c) sv[wid][j + c] = ssq[c];
  __syncthreads();
  const float q0 = sv[0][t] + sv[1][t] + sv[2][t] + sv[3][t];
  const float q1 = sv[0][t + 256] + sv[1][t + 256] + sv[2][t + 256] + sv[3][t + 256];
  atomicAdd(&psum[slice + t], r0);
  atomicAdd(&psum[slice + t + 256], r1);
  atomicAdd(&psq[slice + t], q0);
  atomicAdd(&psq[slice + t + 256], q1);
}

// ---- fold NSLICE partial stats into per-channel scale/shift (bias cancels) ----
__global__ void bn_reduce_kernel(const float* __restrict__ psum, const float* __restrict__ psq,
                                 const float* __restrict__ gamma, const float* __restrict__ beta,
                                 float* __restrict__ scale, float* __restrict__ shift) {
  const int c = threadIdx.x;     // 512
  float s = 0.f, q = 0.f;
#pragma unroll
  for (int k = 0; k < NSLICE; ++k) { s += psum[k * HC + c]; q += psq[k * HC + c]; }
  const float mu = s * (1.0f / N_NODES);
  const float var = q * (1.0f / N_NODES) - mu * mu;
  const float sc = gamma[c] * rsqrtf(var + BN_EPS);
  scale[c] = sc;
  shift[c] = beta[c] - mu * sc;
}

// ---- BN normalize: read bf16 pre-BN rows, write final f32 out ----
__global__ void bn_apply_kernel(const unsigned short* __restrict__ o16,
                                const float* __restrict__ scale,
                                const float* __restrict__ shift,
                                float* __restrict__ out) {
  const int i = blockIdx.x * blockDim.x + threadIdx.x;   // float4 index
  if (i >= N_NODES * HC / 4) return;
  const int j4 = (i & (HC / 4 - 1)) * 4;
  const u16x4 v16 = *(const u16x4*)&o16[(size_t)i * 4];
  const float4 sc = *(const float4*)&scale[j4];
  const float4 sh = *(const float4*)&shift[j4];
  float4 v;
  v.x = bf2f(v16[0]) * sc.x + sh.x;
  v.y = bf2f(v16[1]) * sc.y + sh.y;
  v.z = bf2f(v16[2]) * sc.z + sh.z;
  v.w = bf2f(v16[3]) * sc.w + sh.w;
  ((float4*)out)[i] = v;
}

extern "C" void kernel_launch(void* const* d_in, const int* in_sizes, int n_in,
                              void* d_out, int out_size, void* d_ws, size_t ws_size,
                              hipStream_t stream) {
  const float* x     = (const float*)d_in[0];
  const int*   ei    = (const int*)d_in[1];
  const float* ea    = (const float*)d_in[2];
  const float* W     = (const float*)d_in[3];
  const float* We    = (const float*)d_in[4];
  const float* att_s = (const float*)d_in[5];
  const float* att_d = (const float*)d_in[6];
  const float* att_e = (const float*)d_in[7];
  // d_in[8] = bias: cancels exactly in BatchNorm -> unused
  const float* gamma = (const float*)d_in[9];
  const float* beta  = (const float*)d_in[10];
  float* out = (float*)d_out;
  float* ws  = (float*)d_ws;

  // workspace layout
  unsigned short* H16     = (unsigned short*)ws;                   // N*512 bf16
  float*    a_src   = (float*)(H16 + (size_t)N_NODES * HC);        // N*4
  float*    a_dst   = a_src + N_NODES * NHEAD;                     // N*4
  float*    alphacsr= a_dst + N_NODES * NHEAD;                     // TOT_E*4
  float*    qm      = alphacsr + (size_t)TOT_E * NHEAD;            // 16
  float*    scale   = qm + 16;                                     // 512
  float*    shift   = scale + HC;                                  // 512
  int*      rowstart= (int*)(shift + HC);                          // N+1 (pad 20004)
  int*      csr_src = rowstart + 20004;                            // E
  unsigned short* Bp  = (unsigned short*)(csr_src + N_EDGES);      // 32*16*64*8 ush
  unsigned short* o16 = Bp + (size_t)32 * 16 * 64 * 8;             // N*512 bf16
  // ---- zeroed-every-call block ----
  int*      deg     = (int*)(o16 + (size_t)N_NODES * HC);          // N
  int*      cnt     = deg + N_NODES;                               // N
  float*    msum    = (float*)(cnt + N_NODES);                     // 4
  float*    psum    = msum + 4;                                    // NSLICE*512
  float*    psq     = psum + NSLICE * HC;                          // NSLICE*512

  const size_t zero_bytes =
      (size_t)(N_NODES * 2 + 4 + NSLICE * HC * 2) * sizeof(float);
  hipMemsetAsync(deg, 0, zero_bytes, stream);

  prep_pack_kernel<<<PACK_BLOCKS + PREP_BLOCKS, 256, 0, stream>>>(
      W, Bp, ea, ei, We, att_e, msum, deg, qm);
  scan_kernel<<<1, 1024, 0, stream>>>(deg, rowstart);
  gemm_direct_fused<<<N_NODES / GEMM_BM, 256, 0, stream>>>(x, Bp, att_s, att_d,
                                                           H16, a_src, a_dst);
  scatter_alpha_kernel<<<(TOT_E + 255) / 256, 256, 0, stream>>>(ei, ea, rowstart, cnt,
                                                                a_src, a_dst, msum, qm,
                                                                csr_src, alphacsr);
  agg_fused_kernel<<<AGG_BLOCKS, 256, 0, stream>>>(rowstart, csr_src, alphacsr, H16,
                                                   o16, psum, psq);
  bn_reduce_kernel<<<1, HC, 0, stream>>>(psum, psq, gamma, beta, scale, shift);
  bn_apply_kernel<<<(N_NODES * HC / 4 + 255) / 256, 256, 0, stream>>>(o16, scale, shift, out);
}